// Round 1
// baseline (1132.620 us; speedup 1.0000x reference)
//
#include <hip/hip_runtime.h>
#include <stdint.h>

#define BB 8
#define NN 262144
#define KSEL 6000
#define KPAD 6016
#define NWRD 94            // 94 * 64 = 6016
#define PROP 1000
#define NMS_THR 0.7f
#define CAND_CAP 8192
#define SORT_N 8192
#define MAT_WORDS_PER_BATCH 285760ull   // sum_{w=0..93} 64*(w+1) = 32*94*95

// ---------- helpers ----------
__device__ __forceinline__ unsigned long long shfl_xor_u64(unsigned long long v, int m) {
    unsigned lo = (unsigned)v, hi = (unsigned)(v >> 32);
    lo = __shfl_xor(lo, m);
    hi = __shfl_xor(hi, m);
    return ((unsigned long long)hi << 32) | lo;
}

// IoU exactly as reference: inter / ((areaA + areaB) - inter + 1e-10)
__device__ __forceinline__ float iou_ref(float ay1, float ax1, float ay2, float ax2, float areaA,
                                         float by1, float bx1, float by2, float bx2, float areaB) {
    float y1 = fmaxf(ay1, by1), x1 = fmaxf(ax1, bx1);
    float y2 = fminf(ay2, by2), x2 = fminf(ax2, bx2);
    float inter = __fmul_rn(fmaxf(__fsub_rn(y2, y1), 0.f), fmaxf(__fsub_rn(x2, x1), 0.f));
    float den = __fadd_rn(__fsub_rn(__fadd_rn(areaA, areaB), inter), 1e-10f);
    return __fdiv_rn(inter, den);
}

// ---------- K1: histogram of fixed-point score bins ----------
__global__ void k_hist(const float4* __restrict__ probs, uint32_t* __restrict__ hist) {
    int g = blockIdx.x * blockDim.x + threadIdx.x;   // one float4 = 2 (bg,fg) pairs
    if (g >= BB * NN / 2) return;
    float4 v = probs[g];
    int item0 = g * 2;
    int b = item0 >> 18;                             // N = 2^18
    uint32_t u0 = (uint32_t)(v.y * 16777216.0f); u0 = u0 > 16777215u ? 16777215u : u0;
    uint32_t u1 = (uint32_t)(v.w * 16777216.0f); u1 = u1 > 16777215u ? 16777215u : u1;
    atomicAdd(&hist[(b << 16) + (u0 >> 8)], 1u);
    atomicAdd(&hist[(b << 16) + (u1 >> 8)], 1u);
}

// ---------- K2: find threshold bin b* per batch (suffix count >= KSEL) ----------
__global__ void k_select(const uint32_t* __restrict__ hist, uint32_t* __restrict__ bsel) {
    int b = blockIdx.x;
    const uint32_t* h = hist + (b << 16);
    __shared__ uint32_t csum[256];
    __shared__ int s_cstar;
    __shared__ uint32_t s_cum;
    int t = threadIdx.x;
    const uint4* h4 = (const uint4*)(h + (t << 8));
    uint32_t s = 0;
    for (int k2 = 0; k2 < 64; ++k2) { uint4 q = h4[k2]; s += q.x + q.y + q.z + q.w; }
    csum[t] = s;
    __syncthreads();
    if (t == 0) {
        uint32_t cum = 0; int cs = 0;
        for (int c = 255; c >= 0; --c) {
            if (cum + csum[c] >= (uint32_t)KSEL) { cs = c; break; }
            cum += csum[c];
        }
        s_cstar = cs; s_cum = cum;
    }
    __syncthreads();
    int cs = s_cstar;
    csum[t] = h[(cs << 8) + t];
    __syncthreads();
    if (t == 0) {
        uint32_t cum = s_cum; int bst = cs << 8;
        for (int bin = 255; bin >= 0; --bin) {
            cum += csum[bin];
            if (cum >= (uint32_t)KSEL) { bst = (cs << 8) + bin; break; }
        }
        bsel[b] = (uint32_t)bst;
    }
}

// ---------- K3: compact candidates (bin >= b*) with sortable key ----------
__global__ void k_compact(const float4* __restrict__ probs, const uint32_t* __restrict__ bsel,
                          uint32_t* __restrict__ cnt, uint64_t* __restrict__ cand) {
    int g = blockIdx.x * blockDim.x + threadIdx.x;
    if (g >= BB * NN / 2) return;
    float4 v = probs[g];
    int item0 = g * 2;
    int b = item0 >> 18;
    uint32_t bst = bsel[b];
#pragma unroll
    for (int e = 0; e < 2; ++e) {
        float sc = e ? v.w : v.y;
        uint32_t idx = (uint32_t)((item0 + e) & (NN - 1));
        uint32_t u = (uint32_t)(sc * 16777216.0f); u = u > 16777215u ? 16777215u : u;
        if ((u >> 8) >= bst) {
            uint32_t pos = atomicAdd(&cnt[b], 1u);
            if (pos < CAND_CAP) {
                uint32_t bits = __float_as_uint(sc);
                cand[((uint64_t)b << 13) + pos] = ((uint64_t)bits << 32) | (uint32_t)(~idx);
            }
        }
    }
}

// ---------- K4: per-batch bitonic sort (desc) + gather + decode boxes ----------
__launch_bounds__(1024)
__global__ void k_sort_gather(const uint64_t* __restrict__ cand, const uint32_t* __restrict__ cnt,
                              const float4* __restrict__ rpn_bbox, const float4* __restrict__ anchors,
                              float4* __restrict__ boxes, float* __restrict__ scoresS,
                              float* __restrict__ areas) {
    __shared__ uint64_t key[SORT_N];
    int b = blockIdx.x, t = threadIdx.x;
    uint32_t M = cnt[b]; if (M > CAND_CAP) M = CAND_CAP;
    const uint64_t* cb = cand + ((uint64_t)b << 13);
    for (int s = t; s < SORT_N; s += 1024) key[s] = (s < (int)M) ? cb[s] : 0ull;
    __syncthreads();
    for (int kk = 2; kk <= SORT_N; kk <<= 1) {
        for (int j = kk >> 1; j > 0; j >>= 1) {
            for (int e = t; e < SORT_N; e += 1024) {
                int ixj = e ^ j;
                if (ixj > e) {
                    uint64_t a = key[e], c = key[ixj];
                    bool ddd = ((e & kk) == 0);            // descending overall
                    if ((a < c) == ddd) { key[e] = c; key[ixj] = a; }
                }
            }
            __syncthreads();
        }
    }
    // gather + decode (match numpy op order; no FMA contraction)
    for (int r = t; r < KPAD; r += 1024) {
        float4 bx = make_float4(0.f, 0.f, 0.f, 0.f);
        float sc = 0.f, ar = 0.f;
        if (r < KSEL) {
            uint64_t k64 = key[r];
            uint32_t idx = ~(uint32_t)(k64 & 0xFFFFFFFFull);
            sc = __uint_as_float((uint32_t)(k64 >> 32));
            size_t off = ((size_t)b << 18) + idx;
            float4 a = anchors[off];
            float4 d4 = rpn_bbox[off];
            float d0 = __fmul_rn(d4.x, 0.1f), d1 = __fmul_rn(d4.y, 0.1f);
            float d2 = __fmul_rn(d4.z, 0.2f), d3 = __fmul_rn(d4.w, 0.2f);
            float h = __fsub_rn(a.z, a.x), w = __fsub_rn(a.w, a.y);
            float cy = __fadd_rn(__fadd_rn(a.x, __fmul_rn(0.5f, h)), __fmul_rn(d0, h));
            float cx = __fadd_rn(__fadd_rn(a.y, __fmul_rn(0.5f, w)), __fmul_rn(d1, w));
            float h2 = __fmul_rn(h, expf(d2));
            float w2 = __fmul_rn(w, expf(d3));
            float y1 = __fsub_rn(cy, __fmul_rn(0.5f, h2));
            float x1 = __fsub_rn(cx, __fmul_rn(0.5f, w2));
            float y2 = __fadd_rn(cy, __fmul_rn(0.5f, h2));
            float x2 = __fadd_rn(cx, __fmul_rn(0.5f, w2));
            y1 = fminf(fmaxf(y1, 0.f), 1.f); x1 = fminf(fmaxf(x1, 0.f), 1.f);
            y2 = fminf(fmaxf(y2, 0.f), 1.f); x2 = fminf(fmaxf(x2, 0.f), 1.f);
            bx = make_float4(y1, x1, y2, x2);
            ar = __fmul_rn(__fsub_rn(y2, y1), __fsub_rn(x2, x1));
        }
        boxes[b * KPAD + r] = bx;
        scoresS[b * KPAD + r] = sc;
        areas[b * KPAD + r] = ar;
    }
}

// ---------- K5: IoU bit-matrix, column-word-major triangle ----------
// WORDS[b][w][i] (i < 64*w used) = bits over j in [64w, 64w+64): iou(box_i, box_j) > THR
__global__ void k_matrix(const float4* __restrict__ boxes, const float* __restrict__ areas,
                         uint64_t* __restrict__ mat) {
    const int CH = 24;
    int w = blockIdx.x / CH, c = blockIdx.x % CH;
    int b = blockIdx.y;
    int ni = w << 6;                         // rows used: i < 64*w (diag block never read)
    __shared__ float4 sb[64];
    __shared__ float sa[64];
    int t = threadIdx.x;
    if (t < 64) { int j = (w << 6) + t; sb[t] = boxes[b * KPAD + j]; sa[t] = areas[b * KPAD + j]; }
    __syncthreads();
    int i = (c << 8) + t;
    if (i >= ni) return;
    float4 bi = boxes[b * KPAD + i];
    float ai = areas[b * KPAD + i];
    uint64_t word = 0;
#pragma unroll
    for (int jj = 0; jj < 64; ++jj) {
        float4 bj = sb[jj];
        float iou = iou_ref(bi.x, bi.y, bi.z, bi.w, ai, bj.x, bj.y, bj.z, bj.w, sa[jj]);
        word |= (uint64_t)(iou > NMS_THR) << jj;
    }
    mat[(uint64_t)b * MAT_WORDS_PER_BATCH + (uint64_t)32 * w * (w + 1) + i] = word;
}

// ---------- K6: serial greedy NMS, 1 wave per batch ----------
__launch_bounds__(64)
__global__ void k_nms(const float4* __restrict__ boxes, const float* __restrict__ scoresS,
                      const float* __restrict__ areas, const uint64_t* __restrict__ mat,
                      float* __restrict__ out) {
    int b = blockIdx.x;
    int lane = threadIdx.x;
    __shared__ uint32_t sel[PROP];
    const uint64_t* mb = mat + (uint64_t)b * MAT_WORDS_PER_BATCH;
    float* prop = out + b * (PROP * 4);
    float* psc = out + BB * PROP * 4 + b * PROP;
    int count = 0;
    for (int w = 0; w < NWRD && count < PROP; ++w) {
        int j = (w << 6) + lane;
        float4 bj = boxes[b * KPAD + j];
        float aj = areas[b * KPAD + j];
        float scj = scoresS[b * KPAD + j];
        // rebuild suppression word for this column from all prior selections
        const uint64_t* col = mb + (uint64_t)32 * w * (w + 1);
        unsigned long long a0 = 0, a1 = 0, a2 = 0, a3 = 0;
        int k2 = lane;
        for (; k2 + 192 < count; k2 += 256) {
            a0 |= col[sel[k2]];
            a1 |= col[sel[k2 + 64]];
            a2 |= col[sel[k2 + 128]];
            a3 |= col[sel[k2 + 192]];
        }
        for (; k2 < count; k2 += 64) a0 |= col[sel[k2]];
        unsigned long long acc = (a0 | a1) | (a2 | a3);
#pragma unroll
        for (int off = 32; off; off >>= 1) acc |= shfl_xor_u64(acc, off);
        unsigned long long alive = ~acc;
        if (w == NWRD - 1) alive &= (1ull << 48) - 1;   // only j < 6000 valid in last word
        while (alive && count < PROP) {
            int bp = __builtin_ctzll(alive);
            float by1 = __shfl(bj.x, bp), bx1 = __shfl(bj.y, bp);
            float by2 = __shfl(bj.z, bp), bx2 = __shfl(bj.w, bp);
            float sai = __shfl(aj, bp), ssc = __shfl(scj, bp);
            if (lane == 0) {
                prop[count * 4 + 0] = by1; prop[count * 4 + 1] = bx1;
                prop[count * 4 + 2] = by2; prop[count * 4 + 3] = bx2;
                psc[count] = ssc;
                sel[count] = (uint32_t)((w << 6) + bp);
            }
            // live suppression of current word via ballot
            float iou = iou_ref(by1, bx1, by2, bx2, sai, bj.x, bj.y, bj.z, bj.w, aj);
            unsigned long long bal = __ballot(iou > NMS_THR);
            alive &= ~bal;
            alive &= ~(1ull << bp);
            count++;
        }
        __syncthreads();  // publish sel[] for next crossing
    }
    for (int r = count + lane; r < PROP; r += 64) {
        prop[r * 4 + 0] = 0.f; prop[r * 4 + 1] = 0.f;
        prop[r * 4 + 2] = 0.f; prop[r * 4 + 3] = 0.f;
        psc[r] = 0.f;
    }
}

extern "C" void kernel_launch(void* const* d_in, const int* in_sizes, int n_in,
                              void* d_out, int out_size, void* d_ws, size_t ws_size,
                              hipStream_t stream) {
    const float4* probs = (const float4*)d_in[0];
    const float4* rpn_bbox = (const float4*)d_in[1];
    const float4* anchors = (const float4*)d_in[2];
    float* out = (float*)d_out;

    uint8_t* p = (uint8_t*)d_ws;
    size_t off = 0;
    auto alloc = [&](size_t bytes) -> void* {
        void* q = p + off;
        off += (bytes + 255) & ~(size_t)255;
        return q;
    };
    uint32_t* hist = (uint32_t*)alloc((size_t)BB * 65536 * 4);   // 2 MB
    uint32_t* cnt = (uint32_t*)alloc(BB * 4);
    uint32_t* bsel = (uint32_t*)alloc(BB * 4);
    uint64_t* cand = (uint64_t*)alloc((size_t)BB * CAND_CAP * 8);
    float4* boxes = (float4*)alloc((size_t)BB * KPAD * 16);
    float* scoresS = (float*)alloc((size_t)BB * KPAD * 4);
    float* areas = (float*)alloc((size_t)BB * KPAD * 4);
    uint64_t* mat = (uint64_t*)alloc((size_t)BB * MAT_WORDS_PER_BATCH * 8);  // ~18.3 MB

    if (off > ws_size) {
        // workspace too small: fail loudly but safely
        hipMemsetAsync(d_out, 0, (size_t)out_size * 4, stream);
        return;
    }

    // zero hist + cnt (+bsel, harmless) every call
    hipMemsetAsync(hist, 0, (size_t)BB * 65536 * 4 + 512, stream);

    int thr = 256;
    int ng = (BB * NN / 2 + thr - 1) / thr;
    k_hist<<<ng, thr, 0, stream>>>(probs, hist);
    k_select<<<BB, 256, 0, stream>>>(hist, bsel);
    k_compact<<<ng, thr, 0, stream>>>(probs, bsel, cnt, cand);
    k_sort_gather<<<BB, 1024, 0, stream>>>(cand, cnt, rpn_bbox, anchors, boxes, scoresS, areas);
    dim3 g5(NWRD * 24, BB);
    k_matrix<<<g5, 256, 0, stream>>>(boxes, areas, mat);
    k_nms<<<BB, 64, 0, stream>>>(boxes, scoresS, areas, mat, out);
}

// Round 2
// 496.845 us; speedup vs baseline: 2.2796x; 2.2796x over previous
//
#include <hip/hip_runtime.h>
#include <stdint.h>

#define BB 8
#define NN 262144
#define KSEL 6000
#define KPAD 6016
#define NWRD 94            // 94 * 64 = 6016
#define PROP 1000
#define NMS_THR 0.7f
#define CAND_CAP 8192
#define SORT_N 8192
#define MAT_WORDS_PER_BATCH 285760ull   // sum_{w=0..93} 64*(w+1) = 32*94*95
#define BPB 64             // blocks per batch for hist/compact (4096 items each)
#define STAGE_CAP 768      // per-block candidate staging (expected ~111)

// ---------- helpers ----------
__device__ __forceinline__ unsigned long long shfl_xor_u64(unsigned long long v, int m) {
    unsigned lo = (unsigned)v, hi = (unsigned)(v >> 32);
    lo = __shfl_xor(lo, m);
    hi = __shfl_xor(hi, m);
    return ((unsigned long long)hi << 32) | lo;
}

// IoU exactly as reference: inter / ((areaA + areaB) - inter + 1e-10)
__device__ __forceinline__ float iou_ref(float ay1, float ax1, float ay2, float ax2, float areaA,
                                         float by1, float bx1, float by2, float bx2, float areaB) {
    float y1 = fmaxf(ay1, by1), x1 = fmaxf(ax1, bx1);
    float y2 = fminf(ay2, by2), x2 = fminf(ax2, bx2);
    float inter = __fmul_rn(fmaxf(__fsub_rn(y2, y1), 0.f), fmaxf(__fsub_rn(x2, x1), 0.f));
    float den = __fadd_rn(__fsub_rn(__fadd_rn(areaA, areaB), inter), 1e-10f);
    return __fdiv_rn(inter, den);
}

__device__ __forceinline__ uint32_t score_bin(float sc) {
    uint32_t u = (uint32_t)(sc * 16777216.0f);
    u = u > 16777215u ? 16777215u : u;
    return u >> 16;     // 256 coarse bins
}

// ---------- K1: per-block LDS histogram -> global 256-bin per-batch hist ----------
__global__ void k_hist(const float4* __restrict__ probs, uint32_t* __restrict__ ghist) {
    __shared__ uint32_t lh[256];
    int blk = blockIdx.x;
    int b = blk >> 6;                       // BPB = 64
    int t = threadIdx.x;
    lh[t] = 0u;
    __syncthreads();
    size_t fbase = ((size_t)b * (NN / 2)) + (size_t)(blk & 63) * 2048;
#pragma unroll
    for (int k = 0; k < 8; ++k) {
        float4 v = probs[fbase + k * 256 + t];
        atomicAdd(&lh[score_bin(v.y)], 1u);
        atomicAdd(&lh[score_bin(v.w)], 1u);
    }
    __syncthreads();
    uint32_t c = lh[t];
    if (c) atomicAdd(&ghist[(b << 8) + t], c);
}

// ---------- K2: threshold bin b* per batch (suffix count >= KSEL) ----------
__global__ void k_select(const uint32_t* __restrict__ ghist, uint32_t* __restrict__ bsel) {
    __shared__ uint32_t h[256];
    int b = blockIdx.x, t = threadIdx.x;
    h[t] = ghist[(b << 8) + t];
    __syncthreads();
    if (t == 0) {
        uint32_t cum = 0; int bst = 0;
        for (int c = 255; c >= 0; --c) {
            cum += h[c];
            if (cum >= (uint32_t)KSEL) { bst = c; break; }
        }
        bsel[b] = (uint32_t)bst;
    }
}

// ---------- K3: compact candidates (bin >= b*), block-aggregated reservation ----------
__global__ void k_compact(const float4* __restrict__ probs, const uint32_t* __restrict__ bsel,
                          uint32_t* __restrict__ cnt, uint64_t* __restrict__ cand) {
    __shared__ uint64_t stage[STAGE_CAP];
    __shared__ uint32_t lcnt, lbase;
    int blk = blockIdx.x;
    int b = blk >> 6;
    int t = threadIdx.x;
    if (t == 0) lcnt = 0u;
    __syncthreads();
    uint32_t bst = bsel[b];
    int ibase = (blk & 63) * 4096;          // item index within batch
    size_t fbase = ((size_t)b * (NN / 2)) + (size_t)(blk & 63) * 2048;
#pragma unroll
    for (int k = 0; k < 8; ++k) {
        float4 v = probs[fbase + k * 256 + t];
        int i0 = ibase + (k * 256 + t) * 2;
#pragma unroll
        for (int e = 0; e < 2; ++e) {
            float sc = e ? v.w : v.y;
            if (score_bin(sc) >= bst) {
                uint32_t p = atomicAdd(&lcnt, 1u);
                if (p < STAGE_CAP) {
                    uint32_t bits = __float_as_uint(sc);
                    stage[p] = ((uint64_t)bits << 32) | (uint32_t)(~(uint32_t)(i0 + e));
                }
            }
        }
    }
    __syncthreads();
    if (t == 0) {
        uint32_t m = lcnt > STAGE_CAP ? STAGE_CAP : lcnt;
        lbase = atomicAdd(&cnt[b], m);      // one return-atomic per block
        lcnt = m;
    }
    __syncthreads();
    uint32_t m = lcnt, base = lbase;
    for (uint32_t s = t; s < m; s += 256) {
        uint32_t pos = base + s;
        if (pos < CAND_CAP) cand[((uint64_t)b << 13) + pos] = stage[s];
    }
}

// ---------- K4: per-batch bitonic sort (desc) + gather + decode boxes ----------
__launch_bounds__(1024)
__global__ void k_sort_gather(const uint64_t* __restrict__ cand, const uint32_t* __restrict__ cnt,
                              const float4* __restrict__ rpn_bbox, const float4* __restrict__ anchors,
                              float4* __restrict__ boxes, float* __restrict__ scoresS,
                              float* __restrict__ areas) {
    __shared__ uint64_t key[SORT_N];
    int b = blockIdx.x, t = threadIdx.x;
    uint32_t M = cnt[b]; if (M > CAND_CAP) M = CAND_CAP;
    const uint64_t* cb = cand + ((uint64_t)b << 13);
    for (int s = t; s < SORT_N; s += 1024) key[s] = (s < (int)M) ? cb[s] : 0ull;
    __syncthreads();
    for (int kk = 2; kk <= SORT_N; kk <<= 1) {
        for (int j = kk >> 1; j > 0; j >>= 1) {
            for (int e = t; e < SORT_N; e += 1024) {
                int ixj = e ^ j;
                if (ixj > e) {
                    uint64_t a = key[e], c = key[ixj];
                    bool ddd = ((e & kk) == 0);            // descending overall
                    if ((a < c) == ddd) { key[e] = c; key[ixj] = a; }
                }
            }
            __syncthreads();
        }
    }
    // gather + decode (match numpy op order; no FMA contraction)
    for (int r = t; r < KPAD; r += 1024) {
        float4 bx = make_float4(0.f, 0.f, 0.f, 0.f);
        float sc = 0.f, ar = 0.f;
        if (r < KSEL) {
            uint64_t k64 = key[r];
            uint32_t idx = ~(uint32_t)(k64 & 0xFFFFFFFFull);
            sc = __uint_as_float((uint32_t)(k64 >> 32));
            size_t off = ((size_t)b << 18) + idx;
            float4 a = anchors[off];
            float4 d4 = rpn_bbox[off];
            float d0 = __fmul_rn(d4.x, 0.1f), d1 = __fmul_rn(d4.y, 0.1f);
            float d2 = __fmul_rn(d4.z, 0.2f), d3 = __fmul_rn(d4.w, 0.2f);
            float h = __fsub_rn(a.z, a.x), w = __fsub_rn(a.w, a.y);
            float cy = __fadd_rn(__fadd_rn(a.x, __fmul_rn(0.5f, h)), __fmul_rn(d0, h));
            float cx = __fadd_rn(__fadd_rn(a.y, __fmul_rn(0.5f, w)), __fmul_rn(d1, w));
            float h2 = __fmul_rn(h, expf(d2));
            float w2 = __fmul_rn(w, expf(d3));
            float y1 = __fsub_rn(cy, __fmul_rn(0.5f, h2));
            float x1 = __fsub_rn(cx, __fmul_rn(0.5f, w2));
            float y2 = __fadd_rn(cy, __fmul_rn(0.5f, h2));
            float x2 = __fadd_rn(cx, __fmul_rn(0.5f, w2));
            y1 = fminf(fmaxf(y1, 0.f), 1.f); x1 = fminf(fmaxf(x1, 0.f), 1.f);
            y2 = fminf(fmaxf(y2, 0.f), 1.f); x2 = fminf(fmaxf(x2, 0.f), 1.f);
            bx = make_float4(y1, x1, y2, x2);
            ar = __fmul_rn(__fsub_rn(y2, y1), __fsub_rn(x2, x1));
        }
        boxes[b * KPAD + r] = bx;
        scoresS[b * KPAD + r] = sc;
        areas[b * KPAD + r] = ar;
    }
}

// ---------- K5: IoU bit-matrix, column-word-major triangle ----------
__global__ void k_matrix(const float4* __restrict__ boxes, const float* __restrict__ areas,
                         uint64_t* __restrict__ mat) {
    const int CH = 24;
    int w = blockIdx.x / CH, c = blockIdx.x % CH;
    int b = blockIdx.y;
    int ni = w << 6;                         // rows used: i < 64*w (diag block never read)
    __shared__ float4 sb[64];
    __shared__ float sa[64];
    int t = threadIdx.x;
    if (t < 64) { int j = (w << 6) + t; sb[t] = boxes[b * KPAD + j]; sa[t] = areas[b * KPAD + j]; }
    __syncthreads();
    int i = (c << 8) + t;
    if (i >= ni) return;
    float4 bi = boxes[b * KPAD + i];
    float ai = areas[b * KPAD + i];
    uint64_t word = 0;
#pragma unroll
    for (int jj = 0; jj < 64; ++jj) {
        float4 bj = sb[jj];
        float iou = iou_ref(bi.x, bi.y, bi.z, bi.w, ai, bj.x, bj.y, bj.z, bj.w, sa[jj]);
        word |= (uint64_t)(iou > NMS_THR) << jj;
    }
    mat[(uint64_t)b * MAT_WORDS_PER_BATCH + (uint64_t)32 * w * (w + 1) + i] = word;
}

// ---------- K6: serial greedy NMS, 1 wave per batch ----------
__launch_bounds__(64)
__global__ void k_nms(const float4* __restrict__ boxes, const float* __restrict__ scoresS,
                      const float* __restrict__ areas, const uint64_t* __restrict__ mat,
                      float* __restrict__ out) {
    int b = blockIdx.x;
    int lane = threadIdx.x;
    __shared__ uint32_t sel[PROP];
    const uint64_t* mb = mat + (uint64_t)b * MAT_WORDS_PER_BATCH;
    float* prop = out + b * (PROP * 4);
    float* psc = out + BB * PROP * 4 + b * PROP;
    int count = 0;
    for (int w = 0; w < NWRD && count < PROP; ++w) {
        int j = (w << 6) + lane;
        float4 bj = boxes[b * KPAD + j];
        float aj = areas[b * KPAD + j];
        float scj = scoresS[b * KPAD + j];
        // rebuild suppression word for this column from all prior selections
        const uint64_t* col = mb + (uint64_t)32 * w * (w + 1);
        unsigned long long a0 = 0, a1 = 0, a2 = 0, a3 = 0;
        int k2 = lane;
        for (; k2 + 192 < count; k2 += 256) {
            a0 |= col[sel[k2]];
            a1 |= col[sel[k2 + 64]];
            a2 |= col[sel[k2 + 128]];
            a3 |= col[sel[k2 + 192]];
        }
        for (; k2 < count; k2 += 64) a0 |= col[sel[k2]];
        unsigned long long acc = (a0 | a1) | (a2 | a3);
#pragma unroll
        for (int off = 32; off; off >>= 1) acc |= shfl_xor_u64(acc, off);
        unsigned long long alive = ~acc;
        if (w == NWRD - 1) alive &= (1ull << 48) - 1;   // only j < 6000 valid in last word
        while (alive && count < PROP) {
            int bp = __builtin_ctzll(alive);
            float by1 = __shfl(bj.x, bp), bx1 = __shfl(bj.y, bp);
            float by2 = __shfl(bj.z, bp), bx2 = __shfl(bj.w, bp);
            float sai = __shfl(aj, bp), ssc = __shfl(scj, bp);
            if (lane == 0) {
                prop[count * 4 + 0] = by1; prop[count * 4 + 1] = bx1;
                prop[count * 4 + 2] = by2; prop[count * 4 + 3] = bx2;
                psc[count] = ssc;
                sel[count] = (uint32_t)((w << 6) + bp);
            }
            // live suppression of current word via ballot
            float iou = iou_ref(by1, bx1, by2, bx2, sai, bj.x, bj.y, bj.z, bj.w, aj);
            unsigned long long bal = __ballot(iou > NMS_THR);
            alive &= ~bal;
            alive &= ~(1ull << bp);
            count++;
        }
        __syncthreads();  // publish sel[] for next crossing
    }
    for (int r = count + lane; r < PROP; r += 64) {
        prop[r * 4 + 0] = 0.f; prop[r * 4 + 1] = 0.f;
        prop[r * 4 + 2] = 0.f; prop[r * 4 + 3] = 0.f;
        psc[r] = 0.f;
    }
}

extern "C" void kernel_launch(void* const* d_in, const int* in_sizes, int n_in,
                              void* d_out, int out_size, void* d_ws, size_t ws_size,
                              hipStream_t stream) {
    const float4* probs = (const float4*)d_in[0];
    const float4* rpn_bbox = (const float4*)d_in[1];
    const float4* anchors = (const float4*)d_in[2];
    float* out = (float*)d_out;

    uint8_t* p = (uint8_t*)d_ws;
    size_t off = 0;
    auto alloc = [&](size_t bytes) -> void* {
        void* q = p + off;
        off += (bytes + 255) & ~(size_t)255;
        return q;
    };
    uint32_t* ghist = (uint32_t*)alloc((size_t)BB * 256 * 4);    // 8 KB
    uint32_t* cnt = (uint32_t*)alloc(BB * 4);
    uint32_t* bsel = (uint32_t*)alloc(BB * 4);
    uint64_t* cand = (uint64_t*)alloc((size_t)BB * CAND_CAP * 8);
    float4* boxes = (float4*)alloc((size_t)BB * KPAD * 16);
    float* scoresS = (float*)alloc((size_t)BB * KPAD * 4);
    float* areas = (float*)alloc((size_t)BB * KPAD * 4);
    uint64_t* mat = (uint64_t*)alloc((size_t)BB * MAT_WORDS_PER_BATCH * 8);  // ~18.3 MB

    if (off > ws_size) {
        hipMemsetAsync(d_out, 0, (size_t)out_size * 4, stream);
        return;
    }

    // zero ghist + cnt + bsel every call (they're adjacent, 8 KB + 512 B)
    hipMemsetAsync(ghist, 0, (size_t)BB * 256 * 4 + 512, stream);

    k_hist<<<BB * BPB, 256, 0, stream>>>(probs, ghist);
    k_select<<<BB, 256, 0, stream>>>(ghist, bsel);
    k_compact<<<BB * BPB, 256, 0, stream>>>(probs, bsel, cnt, cand);
    k_sort_gather<<<BB, 1024, 0, stream>>>(cand, cnt, rpn_bbox, anchors, boxes, scoresS, areas);
    dim3 g5(NWRD * 24, BB);
    k_matrix<<<g5, 256, 0, stream>>>(boxes, areas, mat);
    k_nms<<<BB, 64, 0, stream>>>(boxes, scoresS, areas, mat, out);
}

// Round 3
// 344.234 us; speedup vs baseline: 3.2903x; 1.4433x over previous
//
#include <hip/hip_runtime.h>
#include <stdint.h>

#define BB 8
#define NN 262144
#define KSEL 6000
#define KPAD2 6144
#define NW2 24               // 24 words of 256 boxes
#define PROP 1000
#define NMS_THR 0.7f
#define CAND_CAP 8192
#define BPB 64               // blocks per batch for hist/compact (4096 items each)
#define STAGE_CAP 768
#define MAT_U64_PB 282624ull // sum_{W=1..23} 256*W rows * 4 u64 = 512*23*24
#define DIAG_U64_PB 24576ull // 24*256*4

// ---------- helpers ----------
__device__ __forceinline__ unsigned long long shfl_xor_u64(unsigned long long v, int m) {
    unsigned lo = (unsigned)v, hi = (unsigned)(v >> 32);
    lo = __shfl_xor(lo, m);
    hi = __shfl_xor(hi, m);
    return ((unsigned long long)hi << 32) | lo;
}
__device__ __forceinline__ uint64_t rdfl64(uint64_t v) {
    uint32_t lo = __builtin_amdgcn_readfirstlane((uint32_t)v);
    uint32_t hi = __builtin_amdgcn_readfirstlane((uint32_t)(v >> 32));
    return ((uint64_t)hi << 32) | lo;
}
__device__ __forceinline__ uint64_t rdlane64(uint64_t v, uint32_t l) {
    uint32_t lo = __builtin_amdgcn_readlane((uint32_t)v, l);
    uint32_t hi = __builtin_amdgcn_readlane((uint32_t)(v >> 32), l);
    return ((uint64_t)hi << 32) | lo;
}

// IoU exactly as reference: inter / ((areaA + areaB) - inter + 1e-10)
__device__ __forceinline__ float iou_ref(float ay1, float ax1, float ay2, float ax2, float areaA,
                                         float by1, float bx1, float by2, float bx2, float areaB) {
    float y1 = fmaxf(ay1, by1), x1 = fmaxf(ax1, bx1);
    float y2 = fminf(ay2, by2), x2 = fminf(ax2, bx2);
    float inter = __fmul_rn(fmaxf(__fsub_rn(y2, y1), 0.f), fmaxf(__fsub_rn(x2, x1), 0.f));
    float den = __fadd_rn(__fsub_rn(__fadd_rn(areaA, areaB), inter), 1e-10f);
    return __fdiv_rn(inter, den);
}
__device__ __forceinline__ int sup_bit(const float4 bi, float ai, const float4 bj, float aj) {
    return iou_ref(bi.x, bi.y, bi.z, bi.w, ai, bj.x, bj.y, bj.z, bj.w, aj) > NMS_THR ? 1 : 0;
}

__device__ __forceinline__ uint32_t score_bin(float sc) {
    uint32_t u = (uint32_t)(sc * 16777216.0f);
    u = u > 16777215u ? 16777215u : u;
    return u >> 16;
}

// ---------- K1: per-block LDS histogram -> global 256-bin per-batch hist ----------
__global__ void k_hist(const float4* __restrict__ probs, uint32_t* __restrict__ ghist) {
    __shared__ uint32_t lh[256];
    int blk = blockIdx.x;
    int b = blk >> 6;
    int t = threadIdx.x;
    lh[t] = 0u;
    __syncthreads();
    size_t fbase = ((size_t)b * (NN / 2)) + (size_t)(blk & 63) * 2048;
#pragma unroll
    for (int k = 0; k < 8; ++k) {
        float4 v = probs[fbase + k * 256 + t];
        atomicAdd(&lh[score_bin(v.y)], 1u);
        atomicAdd(&lh[score_bin(v.w)], 1u);
    }
    __syncthreads();
    uint32_t c = lh[t];
    if (c) atomicAdd(&ghist[(b << 8) + t], c);
}

// ---------- K2: threshold bin per batch ----------
__global__ void k_select(const uint32_t* __restrict__ ghist, uint32_t* __restrict__ bsel) {
    __shared__ uint32_t h[256];
    int b = blockIdx.x, t = threadIdx.x;
    h[t] = ghist[(b << 8) + t];
    __syncthreads();
    if (t == 0) {
        uint32_t cum = 0; int bst = 0;
        for (int c = 255; c >= 0; --c) {
            cum += h[c];
            if (cum >= (uint32_t)KSEL) { bst = c; break; }
        }
        bsel[b] = (uint32_t)bst;
    }
}

// ---------- K3: compact candidates, block-aggregated reservation ----------
__global__ void k_compact(const float4* __restrict__ probs, const uint32_t* __restrict__ bsel,
                          uint32_t* __restrict__ cnt, uint64_t* __restrict__ cand) {
    __shared__ uint64_t stage[STAGE_CAP];
    __shared__ uint32_t lcnt, lbase;
    int blk = blockIdx.x;
    int b = blk >> 6;
    int t = threadIdx.x;
    if (t == 0) lcnt = 0u;
    __syncthreads();
    uint32_t bst = bsel[b];
    int ibase = (blk & 63) * 4096;
    size_t fbase = ((size_t)b * (NN / 2)) + (size_t)(blk & 63) * 2048;
#pragma unroll
    for (int k = 0; k < 8; ++k) {
        float4 v = probs[fbase + k * 256 + t];
        int i0 = ibase + (k * 256 + t) * 2;
#pragma unroll
        for (int e = 0; e < 2; ++e) {
            float sc = e ? v.w : v.y;
            if (score_bin(sc) >= bst) {
                uint32_t p = atomicAdd(&lcnt, 1u);
                if (p < STAGE_CAP) {
                    uint32_t bits = __float_as_uint(sc);
                    stage[p] = ((uint64_t)bits << 32) | (uint32_t)(~(uint32_t)(i0 + e));
                }
            }
        }
    }
    __syncthreads();
    if (t == 0) {
        uint32_t m = lcnt > STAGE_CAP ? STAGE_CAP : lcnt;
        lbase = atomicAdd(&cnt[b], m);
        lcnt = m;
    }
    __syncthreads();
    uint32_t m = lcnt, base = lbase;
    for (uint32_t s = t; s < m; s += 256) {
        uint32_t pos = base + s;
        if (pos < CAND_CAP) cand[((uint64_t)b << 13) + pos] = stage[s];
    }
}

// ---------- K4a: bitonic phase A — sort 1024-chunks (stages kk=2..1024) ----------
__launch_bounds__(256)
__global__ void k_sort1(const uint32_t* __restrict__ cnt, uint64_t* __restrict__ cand) {
    __shared__ uint64_t key[1024];
    int b = blockIdx.y, ch = blockIdx.x, t = threadIdx.x;
    uint32_t M = cnt[b]; if (M > CAND_CAP) M = CAND_CAP;
    uint64_t* cb = cand + ((uint64_t)b << 13);
    int base = ch << 10;
    for (int i = t; i < 1024; i += 256) key[i] = ((uint32_t)(base + i) < M) ? cb[base + i] : 0ull;
    __syncthreads();
    for (int kk = 2; kk <= 1024; kk <<= 1) {
        for (int j = kk >> 1; j > 0; j >>= 1) {
            for (int e = t; e < 1024; e += 256) {
                int ixj = e ^ j;
                if (ixj > e) {
                    uint64_t a = key[e], c = key[ixj];
                    bool ddd = (((base + e) & kk) == 0);   // global-e direction
                    if ((a < c) == ddd) { key[e] = c; key[ixj] = a; }
                }
            }
            __syncthreads();
        }
    }
    for (int i = t; i < 1024; i += 256) cb[base + i] = key[i];
}

// ---------- K4b: bitonic merge (kk=2048..8192) + gather + decode ----------
__launch_bounds__(1024)
__global__ void k_sort2(const uint64_t* __restrict__ cand,
                        const float4* __restrict__ rpn_bbox, const float4* __restrict__ anchors,
                        float4* __restrict__ boxes, float* __restrict__ scoresS,
                        float* __restrict__ areas) {
    __shared__ uint64_t key[8192];
    int b = blockIdx.x, t = threadIdx.x;
    const uint64_t* cb = cand + ((uint64_t)b << 13);
    for (int s = t; s < 8192; s += 1024) key[s] = cb[s];
    __syncthreads();
    for (int kk = 2048; kk <= 8192; kk <<= 1) {
        for (int j = kk >> 1; j > 0; j >>= 1) {
            for (int e = t; e < 8192; e += 1024) {
                int ixj = e ^ j;
                if (ixj > e) {
                    uint64_t a = key[e], c = key[ixj];
                    bool ddd = ((e & kk) == 0);
                    if ((a < c) == ddd) { key[e] = c; key[ixj] = a; }
                }
            }
            __syncthreads();
        }
    }
    // gather + decode (numpy op order; no FMA contraction)
    for (int r = t; r < KPAD2; r += 1024) {
        float4 bx = make_float4(0.f, 0.f, 0.f, 0.f);
        float sc = 0.f, ar = 0.f;
        if (r < KSEL) {
            uint64_t k64 = key[r];
            uint32_t idx = ~(uint32_t)(k64 & 0xFFFFFFFFull);
            sc = __uint_as_float((uint32_t)(k64 >> 32));
            size_t off = ((size_t)b << 18) + idx;
            float4 a = anchors[off];
            float4 d4 = rpn_bbox[off];
            float d0 = __fmul_rn(d4.x, 0.1f), d1 = __fmul_rn(d4.y, 0.1f);
            float d2 = __fmul_rn(d4.z, 0.2f), d3 = __fmul_rn(d4.w, 0.2f);
            float h = __fsub_rn(a.z, a.x), w = __fsub_rn(a.w, a.y);
            float cy = __fadd_rn(__fadd_rn(a.x, __fmul_rn(0.5f, h)), __fmul_rn(d0, h));
            float cx = __fadd_rn(__fadd_rn(a.y, __fmul_rn(0.5f, w)), __fmul_rn(d1, w));
            float h2 = __fmul_rn(h, expf(d2));
            float w2 = __fmul_rn(w, expf(d3));
            float y1 = __fsub_rn(cy, __fmul_rn(0.5f, h2));
            float x1 = __fsub_rn(cx, __fmul_rn(0.5f, w2));
            float y2 = __fadd_rn(cy, __fmul_rn(0.5f, h2));
            float x2 = __fadd_rn(cx, __fmul_rn(0.5f, w2));
            y1 = fminf(fmaxf(y1, 0.f), 1.f); x1 = fminf(fmaxf(x1, 0.f), 1.f);
            y2 = fminf(fmaxf(y2, 0.f), 1.f); x2 = fminf(fmaxf(x2, 0.f), 1.f);
            bx = make_float4(y1, x1, y2, x2);
            ar = __fmul_rn(__fsub_rn(y2, y1), __fsub_rn(x2, x1));
        }
        boxes[b * KPAD2 + r] = bx;
        scoresS[b * KPAD2 + r] = sc;
        areas[b * KPAD2 + r] = ar;
    }
}

// ---------- K5: suppression bit rows (256-wide words) ----------
// off-diag: mat rows i < 256W vs word W's 256 boxes; diag: rows of word W vs itself.
__launch_bounds__(256)
__global__ void k_matrix(const float4* __restrict__ boxes, const float* __restrict__ areas,
                         uint64_t* __restrict__ mat, uint64_t* __restrict__ diag) {
    __shared__ float4 sb[256];
    __shared__ float sa[256];
    int q = blockIdx.x, b = blockIdx.y, t = threadIdx.x;
    int W, i;
    uint64_t* outrow;
    if (q < NW2) {                       // diagonal chunk
        W = q; i = (W << 8) + t;
        outrow = diag + (uint64_t)b * DIAG_U64_PB + (uint64_t)i * 4;
    } else {                             // off-diagonal chunk (W,c)
        int q2 = q - NW2; W = 1;
        while (q2 >= W) { q2 -= W; ++W; }
        i = (q2 << 8) + t;
        outrow = mat + (uint64_t)b * MAT_U64_PB + 512ull * W * (W - 1) + (uint64_t)i * 4;
    }
    int j0 = W << 8;
    sb[t] = boxes[(size_t)b * KPAD2 + j0 + t];
    sa[t] = areas[(size_t)b * KPAD2 + j0 + t];
    __syncthreads();
    float4 bi = boxes[(size_t)b * KPAD2 + i];
    float ai = areas[(size_t)b * KPAD2 + i];
    uint64_t w0 = 0, w1 = 0, w2 = 0, w3 = 0;
#pragma unroll 2
    for (int jj = 0; jj < 64; ++jj) {
        w0 |= (uint64_t)sup_bit(bi, ai, sb[jj], sa[jj]) << jj;
        w1 |= (uint64_t)sup_bit(bi, ai, sb[64 + jj], sa[64 + jj]) << jj;
        w2 |= (uint64_t)sup_bit(bi, ai, sb[128 + jj], sa[128 + jj]) << jj;
        w3 |= (uint64_t)sup_bit(bi, ai, sb[192 + jj], sa[192 + jj]) << jj;
    }
    ulonglong2* o = (ulonglong2*)outrow;
    ulonglong2 v0; v0.x = w0; v0.y = w1;
    ulonglong2 v1; v1.x = w2; v1.y = w3;
    o[0] = v0; o[1] = v1;
}

// ---------- K6: serial greedy NMS, 1 wave per batch, scalarized ----------
__launch_bounds__(64)
__global__ void k_nms(const float4* __restrict__ boxes, const float* __restrict__ scoresS,
                      const uint64_t* __restrict__ diag, const uint64_t* __restrict__ mat,
                      float* __restrict__ out) {
    int b = blockIdx.x, lane = threadIdx.x;
    __shared__ uint32_t sel[PROP];
    const uint64_t* mb = mat + (uint64_t)b * MAT_U64_PB;
    const ulonglong2* dp = (const ulonglong2*)(diag + (uint64_t)b * DIAG_U64_PB);
    int count = 0;
    for (int W = 0; W < NW2; ++W) {
        if (count >= PROP) break;
        // in-word suppression rows: lane holds rows for boxes lane, lane+64, lane+128, lane+192
        int p0 = (W << 8) + lane;
        ulonglong2 d00 = dp[p0 * 2],          d01 = dp[p0 * 2 + 1];
        ulonglong2 d10 = dp[(p0 + 64) * 2],   d11 = dp[(p0 + 64) * 2 + 1];
        ulonglong2 d20 = dp[(p0 + 128) * 2],  d21 = dp[(p0 + 128) * 2 + 1];
        ulonglong2 d30 = dp[(p0 + 192) * 2],  d31 = dp[(p0 + 192) * 2 + 1];
        // gather suppression from all prior selections (parallel over lanes, 4-deep MLP)
        uint64_t acc0 = 0, acc1 = 0, acc2 = 0, acc3 = 0;
        const uint64_t* col = mb + 512ull * W * (W - 1);
        int k = lane;
        for (; k + 192 < count; k += 256) {
            const ulonglong2* r0 = (const ulonglong2*)(col + 4u * sel[k]);
            const ulonglong2* r1 = (const ulonglong2*)(col + 4u * sel[k + 64]);
            const ulonglong2* r2 = (const ulonglong2*)(col + 4u * sel[k + 128]);
            const ulonglong2* r3 = (const ulonglong2*)(col + 4u * sel[k + 192]);
            ulonglong2 x0 = r0[0], y0 = r0[1], x1 = r1[0], y1 = r1[1];
            ulonglong2 x2 = r2[0], y2 = r2[1], x3 = r3[0], y3 = r3[1];
            acc0 |= x0.x | x1.x | x2.x | x3.x;
            acc1 |= x0.y | x1.y | x2.y | x3.y;
            acc2 |= y0.x | y1.x | y2.x | y3.x;
            acc3 |= y0.y | y1.y | y2.y | y3.y;
        }
        for (; k < count; k += 64) {
            const ulonglong2* r = (const ulonglong2*)(col + 4u * sel[k]);
            ulonglong2 x = r[0], y = r[1];
            acc0 |= x.x; acc1 |= x.y; acc2 |= y.x; acc3 |= y.y;
        }
#pragma unroll
        for (int off = 32; off; off >>= 1) {
            acc0 |= shfl_xor_u64(acc0, off);
            acc1 |= shfl_xor_u64(acc1, off);
            acc2 |= shfl_xor_u64(acc2, off);
            acc3 |= shfl_xor_u64(acc3, off);
        }
        uint64_t a0 = ~rdfl64(acc0), a1 = ~rdfl64(acc1);
        uint64_t a2 = ~rdfl64(acc2), a3 = ~rdfl64(acc3);
        if (W == NW2 - 1) { a1 &= (1ull << 48) - 1; a2 = 0; a3 = 0; }   // j < 6000 valid

#define SUBWORD(S, AS, R0, R1, R2, R3)                                       \
        while (AS && count < PROP) {                                         \
            uint32_t bp = (uint32_t)__builtin_ctzll(AS);                     \
            if (lane == 0) sel[count] = (uint32_t)((W << 8) + (S << 6) + bp);\
            uint64_t q0 = rdlane64(R0, bp), q1 = rdlane64(R1, bp);           \
            uint64_t q2v = rdlane64(R2, bp), q3 = rdlane64(R3, bp);          \
            a0 &= ~q0; a1 &= ~q1; a2 &= ~q2v; a3 &= ~q3;                     \
            AS &= ~(1ull << bp);                                             \
            ++count;                                                         \
        }
        SUBWORD(0, a0, d00.x, d00.y, d01.x, d01.y)
        SUBWORD(1, a1, d10.x, d10.y, d11.x, d11.y)
        SUBWORD(2, a2, d20.x, d20.y, d21.x, d21.y)
        SUBWORD(3, a3, d30.x, d30.y, d31.x, d31.y)
#undef SUBWORD
        __syncthreads();   // publish sel[] for next crossing (single wave: orders LDS)
    }
    __syncthreads();
    // parallel output epilogue
    float* prop = out + b * (PROP * 4);
    float* psc = out + BB * PROP * 4 + b * PROP;
    for (int r = lane; r < PROP; r += 64) {
        if (r < count) {
            uint32_t j = sel[r];
            float4 bx = boxes[(size_t)b * KPAD2 + j];
            *(float4*)(prop + r * 4) = bx;
            psc[r] = scoresS[(size_t)b * KPAD2 + j];
        } else {
            *(float4*)(prop + r * 4) = make_float4(0.f, 0.f, 0.f, 0.f);
            psc[r] = 0.f;
        }
    }
}

extern "C" void kernel_launch(void* const* d_in, const int* in_sizes, int n_in,
                              void* d_out, int out_size, void* d_ws, size_t ws_size,
                              hipStream_t stream) {
    const float4* probs = (const float4*)d_in[0];
    const float4* rpn_bbox = (const float4*)d_in[1];
    const float4* anchors = (const float4*)d_in[2];
    float* out = (float*)d_out;

    uint8_t* p = (uint8_t*)d_ws;
    size_t off = 0;
    auto alloc = [&](size_t bytes) -> void* {
        void* q = p + off;
        off += (bytes + 255) & ~(size_t)255;
        return q;
    };
    uint32_t* ghist = (uint32_t*)alloc((size_t)BB * 256 * 4);
    uint32_t* cnt = (uint32_t*)alloc(BB * 4);
    uint32_t* bsel = (uint32_t*)alloc(BB * 4);
    uint64_t* cand = (uint64_t*)alloc((size_t)BB * CAND_CAP * 8);          // 512 KB
    float4* boxes = (float4*)alloc((size_t)BB * KPAD2 * 16);               // 768 KB
    float* scoresS = (float*)alloc((size_t)BB * KPAD2 * 4);
    float* areas = (float*)alloc((size_t)BB * KPAD2 * 4);
    uint64_t* diag = (uint64_t*)alloc((size_t)BB * DIAG_U64_PB * 8);       // 1.57 MB
    uint64_t* mat = (uint64_t*)alloc((size_t)BB * MAT_U64_PB * 8);         // 18.1 MB

    if (off > ws_size) {
        hipMemsetAsync(d_out, 0, (size_t)out_size * 4, stream);
        return;
    }

    hipMemsetAsync(ghist, 0, (size_t)BB * 256 * 4 + 512, stream);

    k_hist<<<BB * BPB, 256, 0, stream>>>(probs, ghist);
    k_select<<<BB, 256, 0, stream>>>(ghist, bsel);
    k_compact<<<BB * BPB, 256, 0, stream>>>(probs, bsel, cnt, cand);
    dim3 gs1(8, BB);
    k_sort1<<<gs1, 256, 0, stream>>>(cnt, cand);
    k_sort2<<<BB, 1024, 0, stream>>>(cand, rpn_bbox, anchors, boxes, scoresS, areas);
    dim3 gm(NW2 + 276, BB);   // 24 diag chunks + sum_{W=1..23} W off-diag chunks
    k_matrix<<<gm, 256, 0, stream>>>(boxes, areas, mat, diag);
    k_nms<<<BB, 64, 0, stream>>>(boxes, scoresS, diag, mat, out);
}

// Round 4
// 306.232 us; speedup vs baseline: 3.6986x; 1.1241x over previous
//
#include <hip/hip_runtime.h>
#include <stdint.h>

#define BB 8
#define NN 262144
#define KSEL 6000
#define KPAD2 6144
#define NW2 24               // 24 words of 256 boxes
#define PROP 1000
#define NMS_THR 0.7f
#define CAND_CAP 8192
#define BPB 64               // blocks per batch for hist/compact (4096 items each)
#define STAGE_CAP 768
#define MAT_U64_PB 282624ull // sum_{W=1..23} 256*W rows * 4 u64 = 512*23*24
#define DIAG_U64_PB 24576ull // 24*256*4

// ---------- helpers ----------
__device__ __forceinline__ unsigned long long shfl_xor_u64(unsigned long long v, int m) {
    unsigned lo = (unsigned)v, hi = (unsigned)(v >> 32);
    lo = __shfl_xor(lo, m);
    hi = __shfl_xor(hi, m);
    return ((unsigned long long)hi << 32) | lo;
}
__device__ __forceinline__ uint64_t rdfl64(uint64_t v) {
    uint32_t lo = __builtin_amdgcn_readfirstlane((uint32_t)v);
    uint32_t hi = __builtin_amdgcn_readfirstlane((uint32_t)(v >> 32));
    return ((uint64_t)hi << 32) | lo;
}
__device__ __forceinline__ uint64_t rdlane64(uint64_t v, uint32_t l) {
    uint32_t lo = __builtin_amdgcn_readlane((uint32_t)v, l);
    uint32_t hi = __builtin_amdgcn_readlane((uint32_t)(v >> 32), l);
    return ((uint64_t)hi << 32) | lo;
}

// Exact replacement for RN(inter/den) > 0.7f (den > 0 always):
//   RN(q) > c  <=>  q >= M, M = c + 2^-25 (midpoint; tie rounds to even = c_next > c).
//   M has 25-bit significand, den 24 bits -> M*den exact in f64; comparison exact.
__device__ __forceinline__ uint32_t sup_bit(const float4 bi, float ai, const float4 bj, float aj) {
    float y1 = fmaxf(bi.x, bj.x), x1 = fmaxf(bi.y, bj.y);
    float y2 = fminf(bi.z, bj.z), x2 = fminf(bi.w, bj.w);
    float inter = __fmul_rn(fmaxf(__fsub_rn(y2, y1), 0.f), fmaxf(__fsub_rn(x2, x1), 0.f));
    float den = __fadd_rn(__fsub_rn(__fadd_rn(ai, aj), inter), 1e-10f);
    const double MSUP = 23488103.0 / 33554432.0;   // 0.7f + 2^-25, exact
    return (double)inter >= MSUP * (double)den;
}

__device__ __forceinline__ uint32_t score_bin(float sc) {
    uint32_t u = (uint32_t)(sc * 16777216.0f);
    u = u > 16777215u ? 16777215u : u;
    return u >> 16;
}

// ---------- K1: per-block LDS histogram -> global 256-bin per-batch hist ----------
__global__ void k_hist(const float4* __restrict__ probs, uint32_t* __restrict__ ghist) {
    __shared__ uint32_t lh[256];
    int blk = blockIdx.x;
    int b = blk >> 6;
    int t = threadIdx.x;
    lh[t] = 0u;
    __syncthreads();
    size_t fbase = ((size_t)b * (NN / 2)) + (size_t)(blk & 63) * 2048;
#pragma unroll
    for (int k = 0; k < 8; ++k) {
        float4 v = probs[fbase + k * 256 + t];
        atomicAdd(&lh[score_bin(v.y)], 1u);
        atomicAdd(&lh[score_bin(v.w)], 1u);
    }
    __syncthreads();
    uint32_t c = lh[t];
    if (c) atomicAdd(&ghist[(b << 8) + t], c);
}

// ---------- K2: threshold bin per batch ----------
__global__ void k_select(const uint32_t* __restrict__ ghist, uint32_t* __restrict__ bsel) {
    __shared__ uint32_t h[256];
    int b = blockIdx.x, t = threadIdx.x;
    h[t] = ghist[(b << 8) + t];
    __syncthreads();
    if (t == 0) {
        uint32_t cum = 0; int bst = 0;
        for (int c = 255; c >= 0; --c) {
            cum += h[c];
            if (cum >= (uint32_t)KSEL) { bst = c; break; }
        }
        bsel[b] = (uint32_t)bst;
    }
}

// ---------- K3: compact candidates, block-aggregated reservation ----------
__global__ void k_compact(const float4* __restrict__ probs, const uint32_t* __restrict__ bsel,
                          uint32_t* __restrict__ cnt, uint64_t* __restrict__ cand) {
    __shared__ uint64_t stage[STAGE_CAP];
    __shared__ uint32_t lcnt, lbase;
    int blk = blockIdx.x;
    int b = blk >> 6;
    int t = threadIdx.x;
    if (t == 0) lcnt = 0u;
    __syncthreads();
    uint32_t bst = bsel[b];
    int ibase = (blk & 63) * 4096;
    size_t fbase = ((size_t)b * (NN / 2)) + (size_t)(blk & 63) * 2048;
#pragma unroll
    for (int k = 0; k < 8; ++k) {
        float4 v = probs[fbase + k * 256 + t];
        int i0 = ibase + (k * 256 + t) * 2;
#pragma unroll
        for (int e = 0; e < 2; ++e) {
            float sc = e ? v.w : v.y;
            if (score_bin(sc) >= bst) {
                uint32_t p = atomicAdd(&lcnt, 1u);
                if (p < STAGE_CAP) {
                    uint32_t bits = __float_as_uint(sc);
                    stage[p] = ((uint64_t)bits << 32) | (uint32_t)(~(uint32_t)(i0 + e));
                }
            }
        }
    }
    __syncthreads();
    if (t == 0) {
        uint32_t m = lcnt > STAGE_CAP ? STAGE_CAP : lcnt;
        lbase = atomicAdd(&cnt[b], m);
        lcnt = m;
    }
    __syncthreads();
    uint32_t m = lcnt, base = lbase;
    for (uint32_t s = t; s < m; s += 256) {
        uint32_t pos = base + s;
        if (pos < CAND_CAP) cand[((uint64_t)b << 13) + pos] = stage[s];
    }
}

// ---------- K4a: bitonic phase A — sort 1024-chunks (stages kk=2..1024) ----------
__launch_bounds__(256)
__global__ void k_sort1(const uint32_t* __restrict__ cnt, uint64_t* __restrict__ cand) {
    __shared__ uint64_t key[1024];
    int b = blockIdx.y, ch = blockIdx.x, t = threadIdx.x;
    uint32_t M = cnt[b]; if (M > CAND_CAP) M = CAND_CAP;
    uint64_t* cb = cand + ((uint64_t)b << 13);
    int base = ch << 10;
    for (int i = t; i < 1024; i += 256) key[i] = ((uint32_t)(base + i) < M) ? cb[base + i] : 0ull;
    __syncthreads();
    for (int kk = 2; kk <= 1024; kk <<= 1) {
        for (int j = kk >> 1; j > 0; j >>= 1) {
            for (int e = t; e < 1024; e += 256) {
                int ixj = e ^ j;
                if (ixj > e) {
                    uint64_t a = key[e], c = key[ixj];
                    bool ddd = (((base + e) & kk) == 0);   // global-e direction
                    if ((a < c) == ddd) { key[e] = c; key[ixj] = a; }
                }
            }
            __syncthreads();
        }
    }
    for (int i = t; i < 1024; i += 256) cb[base + i] = key[i];
}

// ---------- K4b: bitonic merge (kk=2048..8192) + gather + decode ----------
__launch_bounds__(1024)
__global__ void k_sort2(const uint64_t* __restrict__ cand,
                        const float4* __restrict__ rpn_bbox, const float4* __restrict__ anchors,
                        float4* __restrict__ boxes, float* __restrict__ scoresS,
                        float* __restrict__ areas) {
    __shared__ uint64_t key[8192];
    int b = blockIdx.x, t = threadIdx.x;
    const uint64_t* cb = cand + ((uint64_t)b << 13);
    for (int s = t; s < 8192; s += 1024) key[s] = cb[s];
    __syncthreads();
    for (int kk = 2048; kk <= 8192; kk <<= 1) {
        for (int j = kk >> 1; j > 0; j >>= 1) {
            for (int e = t; e < 8192; e += 1024) {
                int ixj = e ^ j;
                if (ixj > e) {
                    uint64_t a = key[e], c = key[ixj];
                    bool ddd = ((e & kk) == 0);
                    if ((a < c) == ddd) { key[e] = c; key[ixj] = a; }
                }
            }
            __syncthreads();
        }
    }
    // gather + decode (numpy op order; no FMA contraction)
    for (int r = t; r < KPAD2; r += 1024) {
        float4 bx = make_float4(0.f, 0.f, 0.f, 0.f);
        float sc = 0.f, ar = 0.f;
        if (r < KSEL) {
            uint64_t k64 = key[r];
            uint32_t idx = ~(uint32_t)(k64 & 0xFFFFFFFFull);
            sc = __uint_as_float((uint32_t)(k64 >> 32));
            size_t off = ((size_t)b << 18) + idx;
            float4 a = anchors[off];
            float4 d4 = rpn_bbox[off];
            float d0 = __fmul_rn(d4.x, 0.1f), d1 = __fmul_rn(d4.y, 0.1f);
            float d2 = __fmul_rn(d4.z, 0.2f), d3 = __fmul_rn(d4.w, 0.2f);
            float h = __fsub_rn(a.z, a.x), w = __fsub_rn(a.w, a.y);
            float cy = __fadd_rn(__fadd_rn(a.x, __fmul_rn(0.5f, h)), __fmul_rn(d0, h));
            float cx = __fadd_rn(__fadd_rn(a.y, __fmul_rn(0.5f, w)), __fmul_rn(d1, w));
            float h2 = __fmul_rn(h, expf(d2));
            float w2 = __fmul_rn(w, expf(d3));
            float y1 = __fsub_rn(cy, __fmul_rn(0.5f, h2));
            float x1 = __fsub_rn(cx, __fmul_rn(0.5f, w2));
            float y2 = __fadd_rn(cy, __fmul_rn(0.5f, h2));
            float x2 = __fadd_rn(cx, __fmul_rn(0.5f, w2));
            y1 = fminf(fmaxf(y1, 0.f), 1.f); x1 = fminf(fmaxf(x1, 0.f), 1.f);
            y2 = fminf(fmaxf(y2, 0.f), 1.f); x2 = fminf(fmaxf(x2, 0.f), 1.f);
            bx = make_float4(y1, x1, y2, x2);
            ar = __fmul_rn(__fsub_rn(y2, y1), __fsub_rn(x2, x1));
        }
        boxes[b * KPAD2 + r] = bx;
        scoresS[b * KPAD2 + r] = sc;
        areas[b * KPAD2 + r] = ar;
    }
}

// ---------- K5: suppression bit rows (256-wide words), 2 rows/thread ----------
__launch_bounds__(128)
__global__ void k_matrix(const float4* __restrict__ boxes, const float* __restrict__ areas,
                         uint64_t* __restrict__ mat, uint64_t* __restrict__ diag) {
    __shared__ float4 sb[256];
    __shared__ float sa[256];
    int q = blockIdx.x, b = blockIdx.y, t = threadIdx.x;
    int W, ibase;
    if (q < NW2) { W = q; ibase = W << 8; }
    else {
        int q2 = q - NW2; W = 1;
        while (q2 >= W) { q2 -= W; ++W; }
        ibase = q2 << 8;
    }
    size_t bb = (size_t)b * KPAD2;
    int j0 = W << 8;
    sb[t] = boxes[bb + j0 + t];
    sb[t + 128] = boxes[bb + j0 + t + 128];
    sa[t] = areas[bb + j0 + t];
    sa[t + 128] = areas[bb + j0 + t + 128];
    __syncthreads();
    int iA = ibase + t, iB = ibase + t + 128;
    float4 bA = boxes[bb + iA], bB = boxes[bb + iB];
    float aA = areas[bb + iA], aB = areas[bb + iB];
    uint32_t accA[8] = {0, 0, 0, 0, 0, 0, 0, 0};
    uint32_t accB[8] = {0, 0, 0, 0, 0, 0, 0, 0};
#pragma unroll 4
    for (int jj = 0; jj < 32; ++jj) {
#pragma unroll
        for (int s = 0; s < 4; ++s) {
            int j = (s << 6) + jj;
            float4 bj = sb[j]; float aj = sa[j];
            accA[s * 2] |= sup_bit(bA, aA, bj, aj) << jj;
            accB[s * 2] |= sup_bit(bB, aB, bj, aj) << jj;
        }
    }
#pragma unroll 4
    for (int jj = 32; jj < 64; ++jj) {
#pragma unroll
        for (int s = 0; s < 4; ++s) {
            int j = (s << 6) + jj;
            float4 bj = sb[j]; float aj = sa[j];
            accA[s * 2 + 1] |= sup_bit(bA, aA, bj, aj) << (jj - 32);
            accB[s * 2 + 1] |= sup_bit(bB, aB, bj, aj) << (jj - 32);
        }
    }
    uint64_t* rowA;
    uint64_t* rowB;
    if (q < NW2) {
        uint64_t dbase = (uint64_t)b * DIAG_U64_PB;
        rowA = diag + dbase + (uint64_t)iA * 4;
        rowB = diag + dbase + (uint64_t)iB * 4;
    } else {
        uint64_t mbase = (uint64_t)b * MAT_U64_PB + 512ull * W * (W - 1);
        rowA = mat + mbase + (uint64_t)iA * 4;
        rowB = mat + mbase + (uint64_t)iB * 4;
    }
    ulonglong2 vA0, vA1, vB0, vB1;
    vA0.x = (uint64_t)accA[0] | ((uint64_t)accA[1] << 32);
    vA0.y = (uint64_t)accA[2] | ((uint64_t)accA[3] << 32);
    vA1.x = (uint64_t)accA[4] | ((uint64_t)accA[5] << 32);
    vA1.y = (uint64_t)accA[6] | ((uint64_t)accA[7] << 32);
    vB0.x = (uint64_t)accB[0] | ((uint64_t)accB[1] << 32);
    vB0.y = (uint64_t)accB[2] | ((uint64_t)accB[3] << 32);
    vB1.x = (uint64_t)accB[4] | ((uint64_t)accB[5] << 32);
    vB1.y = (uint64_t)accB[6] | ((uint64_t)accB[7] << 32);
    ((ulonglong2*)rowA)[0] = vA0; ((ulonglong2*)rowA)[1] = vA1;
    ((ulonglong2*)rowB)[0] = vB0; ((ulonglong2*)rowB)[1] = vB1;
}

// ---------- K6: serial greedy NMS, 1 wave per batch, scalarized ----------
__launch_bounds__(64)
__global__ void k_nms(const float4* __restrict__ boxes, const float* __restrict__ scoresS,
                      const uint64_t* __restrict__ diag, const uint64_t* __restrict__ mat,
                      float* __restrict__ out) {
    int b = blockIdx.x, lane = threadIdx.x;
    __shared__ uint32_t sel[PROP];
    const uint64_t* mb = mat + (uint64_t)b * MAT_U64_PB;
    const ulonglong2* dp = (const ulonglong2*)(diag + (uint64_t)b * DIAG_U64_PB);
    int count = 0;
    for (int W = 0; W < NW2; ++W) {
        if (count >= PROP) break;
        // in-word suppression rows: lane holds rows for boxes lane, lane+64, lane+128, lane+192
        int p0 = (W << 8) + lane;
        ulonglong2 d00 = dp[p0 * 2],          d01 = dp[p0 * 2 + 1];
        ulonglong2 d10 = dp[(p0 + 64) * 2],   d11 = dp[(p0 + 64) * 2 + 1];
        ulonglong2 d20 = dp[(p0 + 128) * 2],  d21 = dp[(p0 + 128) * 2 + 1];
        ulonglong2 d30 = dp[(p0 + 192) * 2],  d31 = dp[(p0 + 192) * 2 + 1];
        // gather suppression from all prior selections (parallel over lanes, 4-deep MLP)
        uint64_t acc0 = 0, acc1 = 0, acc2 = 0, acc3 = 0;
        const uint64_t* col = mb + 512ull * W * (W - 1);
        int k = lane;
        for (; k + 192 < count; k += 256) {
            const ulonglong2* r0 = (const ulonglong2*)(col + 4u * sel[k]);
            const ulonglong2* r1 = (const ulonglong2*)(col + 4u * sel[k + 64]);
            const ulonglong2* r2 = (const ulonglong2*)(col + 4u * sel[k + 128]);
            const ulonglong2* r3 = (const ulonglong2*)(col + 4u * sel[k + 192]);
            ulonglong2 x0 = r0[0], y0 = r0[1], x1 = r1[0], y1 = r1[1];
            ulonglong2 x2 = r2[0], y2 = r2[1], x3 = r3[0], y3 = r3[1];
            acc0 |= x0.x | x1.x | x2.x | x3.x;
            acc1 |= x0.y | x1.y | x2.y | x3.y;
            acc2 |= y0.x | y1.x | y2.x | y3.x;
            acc3 |= y0.y | y1.y | y2.y | y3.y;
        }
        for (; k < count; k += 64) {
            const ulonglong2* r = (const ulonglong2*)(col + 4u * sel[k]);
            ulonglong2 x = r[0], y = r[1];
            acc0 |= x.x; acc1 |= x.y; acc2 |= y.x; acc3 |= y.y;
        }
#pragma unroll
        for (int off = 32; off; off >>= 1) {
            acc0 |= shfl_xor_u64(acc0, off);
            acc1 |= shfl_xor_u64(acc1, off);
            acc2 |= shfl_xor_u64(acc2, off);
            acc3 |= shfl_xor_u64(acc3, off);
        }
        uint64_t a0 = ~rdfl64(acc0), a1 = ~rdfl64(acc1);
        uint64_t a2 = ~rdfl64(acc2), a3 = ~rdfl64(acc3);
        if (W == NW2 - 1) { a1 &= (1ull << 48) - 1; a2 = 0; a3 = 0; }   // j < 6000 valid

#define SUBWORD(S, AS, R0, R1, R2, R3)                                       \
        while (AS && count < PROP) {                                         \
            uint32_t bp = (uint32_t)__builtin_ctzll(AS);                     \
            if (lane == 0) sel[count] = (uint32_t)((W << 8) + (S << 6) + bp);\
            uint64_t q0 = rdlane64(R0, bp), q1 = rdlane64(R1, bp);           \
            uint64_t q2v = rdlane64(R2, bp), q3 = rdlane64(R3, bp);          \
            a0 &= ~q0; a1 &= ~q1; a2 &= ~q2v; a3 &= ~q3;                     \
            AS &= ~(1ull << bp);                                             \
            ++count;                                                         \
        }
        SUBWORD(0, a0, d00.x, d00.y, d01.x, d01.y)
        SUBWORD(1, a1, d10.x, d10.y, d11.x, d11.y)
        SUBWORD(2, a2, d20.x, d20.y, d21.x, d21.y)
        SUBWORD(3, a3, d30.x, d30.y, d31.x, d31.y)
#undef SUBWORD
        __syncthreads();   // publish sel[] for next crossing (single wave: orders LDS)
    }
    __syncthreads();
    // parallel output epilogue
    float* prop = out + b * (PROP * 4);
    float* psc = out + BB * PROP * 4 + b * PROP;
    for (int r = lane; r < PROP; r += 64) {
        if (r < count) {
            uint32_t j = sel[r];
            float4 bx = boxes[(size_t)b * KPAD2 + j];
            *(float4*)(prop + r * 4) = bx;
            psc[r] = scoresS[(size_t)b * KPAD2 + j];
        } else {
            *(float4*)(prop + r * 4) = make_float4(0.f, 0.f, 0.f, 0.f);
            psc[r] = 0.f;
        }
    }
}

extern "C" void kernel_launch(void* const* d_in, const int* in_sizes, int n_in,
                              void* d_out, int out_size, void* d_ws, size_t ws_size,
                              hipStream_t stream) {
    const float4* probs = (const float4*)d_in[0];
    const float4* rpn_bbox = (const float4*)d_in[1];
    const float4* anchors = (const float4*)d_in[2];
    float* out = (float*)d_out;

    uint8_t* p = (uint8_t*)d_ws;
    size_t off = 0;
    auto alloc = [&](size_t bytes) -> void* {
        void* q = p + off;
        off += (bytes + 255) & ~(size_t)255;
        return q;
    };
    uint32_t* ghist = (uint32_t*)alloc((size_t)BB * 256 * 4);
    uint32_t* cnt = (uint32_t*)alloc(BB * 4);
    uint32_t* bsel = (uint32_t*)alloc(BB * 4);
    uint64_t* cand = (uint64_t*)alloc((size_t)BB * CAND_CAP * 8);          // 512 KB
    float4* boxes = (float4*)alloc((size_t)BB * KPAD2 * 16);               // 768 KB
    float* scoresS = (float*)alloc((size_t)BB * KPAD2 * 4);
    float* areas = (float*)alloc((size_t)BB * KPAD2 * 4);
    uint64_t* diag = (uint64_t*)alloc((size_t)BB * DIAG_U64_PB * 8);       // 1.57 MB
    uint64_t* mat = (uint64_t*)alloc((size_t)BB * MAT_U64_PB * 8);         // 18.1 MB

    if (off > ws_size) {
        hipMemsetAsync(d_out, 0, (size_t)out_size * 4, stream);
        return;
    }

    hipMemsetAsync(ghist, 0, (size_t)BB * 256 * 4 + 512, stream);

    k_hist<<<BB * BPB, 256, 0, stream>>>(probs, ghist);
    k_select<<<BB, 256, 0, stream>>>(ghist, bsel);
    k_compact<<<BB * BPB, 256, 0, stream>>>(probs, bsel, cnt, cand);
    dim3 gs1(8, BB);
    k_sort1<<<gs1, 256, 0, stream>>>(cnt, cand);
    k_sort2<<<BB, 1024, 0, stream>>>(cand, rpn_bbox, anchors, boxes, scoresS, areas);
    dim3 gm(NW2 + 276, BB);   // 24 diag chunks + sum_{W=1..23} W off-diag chunks
    k_matrix<<<gm, 128, 0, stream>>>(boxes, areas, mat, diag);
    k_nms<<<BB, 64, 0, stream>>>(boxes, scoresS, diag, mat, out);
}

// Round 5
// 297.386 us; speedup vs baseline: 3.8086x; 1.0297x over previous
//
#include <hip/hip_runtime.h>
#include <stdint.h>

#define BB 8
#define NN 262144
#define KSEL 6000
#define KPAD2 6144
#define NW2 24               // 24 words of 256 boxes
#define PROP 1000
#define NMS_THR 0.7f
#define CAND_CAP 8192
#define BPB 64               // blocks per batch for hist/compact (4096 items each)
#define STAGE_CAP 768
#define MAT_U64_PB 282624ull // sum_{W=1..23} 256*W rows * 4 u64 = 512*23*24
#define DIAG_U64_PB 24576ull // 24*256*4

// ---------- helpers ----------
__device__ __forceinline__ unsigned long long shfl_xor_u64(unsigned long long v, int m) {
    unsigned lo = (unsigned)v, hi = (unsigned)(v >> 32);
    lo = __shfl_xor(lo, m);
    hi = __shfl_xor(hi, m);
    return ((unsigned long long)hi << 32) | lo;
}
__device__ __forceinline__ uint64_t rdlane64(uint64_t v, uint32_t l) {
    uint32_t lo = __builtin_amdgcn_readlane((uint32_t)v, l);
    uint32_t hi = __builtin_amdgcn_readlane((uint32_t)(v >> 32), l);
    return ((uint64_t)hi << 32) | lo;
}

// Exact replacement for RN(inter/den) > 0.7f (den > 0 always):
//   RN(q) > c  <=>  q >= M, M = c + 2^-25 (midpoint; tie rounds to even = c_next > c).
//   M has 25-bit significand, den 24 bits -> M*den exact in f64; comparison exact.
__device__ __forceinline__ uint32_t sup_bit(const float4 bi, float ai, const float4 bj, float aj) {
    float y1 = fmaxf(bi.x, bj.x), x1 = fmaxf(bi.y, bj.y);
    float y2 = fminf(bi.z, bj.z), x2 = fminf(bi.w, bj.w);
    float inter = __fmul_rn(fmaxf(__fsub_rn(y2, y1), 0.f), fmaxf(__fsub_rn(x2, x1), 0.f));
    float den = __fadd_rn(__fsub_rn(__fadd_rn(ai, aj), inter), 1e-10f);
    const double MSUP = 23488103.0 / 33554432.0;   // 0.7f + 2^-25, exact
    return (double)inter >= MSUP * (double)den;
}

__device__ __forceinline__ uint32_t score_bin(float sc) {
    uint32_t u = (uint32_t)(sc * 16777216.0f);
    u = u > 16777215u ? 16777215u : u;
    return u >> 16;
}

// ---------- K1: per-block LDS histogram -> global 256-bin per-batch hist ----------
__global__ void k_hist(const float4* __restrict__ probs, uint32_t* __restrict__ ghist) {
    __shared__ uint32_t lh[256];
    int blk = blockIdx.x;
    int b = blk >> 6;
    int t = threadIdx.x;
    lh[t] = 0u;
    __syncthreads();
    size_t fbase = ((size_t)b * (NN / 2)) + (size_t)(blk & 63) * 2048;
#pragma unroll
    for (int k = 0; k < 8; ++k) {
        float4 v = probs[fbase + k * 256 + t];
        atomicAdd(&lh[score_bin(v.y)], 1u);
        atomicAdd(&lh[score_bin(v.w)], 1u);
    }
    __syncthreads();
    uint32_t c = lh[t];
    if (c) atomicAdd(&ghist[(b << 8) + t], c);
}

// ---------- K3: compact candidates (threshold derived in-block), block-aggregated ----------
__global__ void k_compact(const float4* __restrict__ probs, const uint32_t* __restrict__ ghist,
                          uint32_t* __restrict__ cnt, uint64_t* __restrict__ cand) {
    __shared__ uint64_t stage[STAGE_CAP];
    __shared__ uint32_t lh[256];
    __shared__ uint32_t s_bst, lcnt, lbase;
    int blk = blockIdx.x;
    int b = blk >> 6;
    int t = threadIdx.x;
    lh[t] = ghist[(b << 8) + t];
    if (t == 0) lcnt = 0u;
    __syncthreads();
    if (t == 0) {
        uint32_t cum = 0; uint32_t bst = 0;
        for (int c = 255; c >= 0; --c) {
            cum += lh[c];
            if (cum >= (uint32_t)KSEL) { bst = (uint32_t)c; break; }
        }
        s_bst = bst;
    }
    __syncthreads();
    uint32_t bst = s_bst;
    int ibase = (blk & 63) * 4096;
    size_t fbase = ((size_t)b * (NN / 2)) + (size_t)(blk & 63) * 2048;
#pragma unroll
    for (int k = 0; k < 8; ++k) {
        float4 v = probs[fbase + k * 256 + t];
        int i0 = ibase + (k * 256 + t) * 2;
#pragma unroll
        for (int e = 0; e < 2; ++e) {
            float sc = e ? v.w : v.y;
            if (score_bin(sc) >= bst) {
                uint32_t p = atomicAdd(&lcnt, 1u);
                if (p < STAGE_CAP) {
                    uint32_t bits = __float_as_uint(sc);
                    stage[p] = ((uint64_t)bits << 32) | (uint32_t)(~(uint32_t)(i0 + e));
                }
            }
        }
    }
    __syncthreads();
    if (t == 0) {
        uint32_t m = lcnt > STAGE_CAP ? STAGE_CAP : lcnt;
        lbase = atomicAdd(&cnt[b], m);
        lcnt = m;
    }
    __syncthreads();
    uint32_t m = lcnt, base = lbase;
    for (uint32_t s = t; s < m; s += 256) {
        uint32_t pos = base + s;
        if (pos < CAND_CAP) cand[((uint64_t)b << 13) + pos] = stage[s];
    }
}

// ---------- K4a: bitonic phase A — sort 1024-chunks (stages kk=2..1024) ----------
__launch_bounds__(256)
__global__ void k_sort1(const uint32_t* __restrict__ cnt, uint64_t* __restrict__ cand) {
    __shared__ uint64_t key[1024];
    int b = blockIdx.y, ch = blockIdx.x, t = threadIdx.x;
    uint32_t M = cnt[b]; if (M > CAND_CAP) M = CAND_CAP;
    uint64_t* cb = cand + ((uint64_t)b << 13);
    int base = ch << 10;
    for (int i = t; i < 1024; i += 256) key[i] = ((uint32_t)(base + i) < M) ? cb[base + i] : 0ull;
    __syncthreads();
    for (int kk = 2; kk <= 1024; kk <<= 1) {
        for (int j = kk >> 1; j > 0; j >>= 1) {
            for (int e = t; e < 1024; e += 256) {
                int ixj = e ^ j;
                if (ixj > e) {
                    uint64_t a = key[e], c = key[ixj];
                    bool ddd = (((base + e) & kk) == 0);   // global-e direction
                    if ((a < c) == ddd) { key[e] = c; key[ixj] = a; }
                }
            }
            __syncthreads();
        }
    }
    for (int i = t; i < 1024; i += 256) cb[base + i] = key[i];
}

// ---------- K4b: bitonic merge (kk=2048..8192) + gather + decode ----------
__launch_bounds__(1024)
__global__ void k_sort2(const uint64_t* __restrict__ cand,
                        const float4* __restrict__ rpn_bbox, const float4* __restrict__ anchors,
                        float4* __restrict__ boxes, float* __restrict__ scoresS,
                        float* __restrict__ areas) {
    __shared__ uint64_t key[8192];
    int b = blockIdx.x, t = threadIdx.x;
    const uint64_t* cb = cand + ((uint64_t)b << 13);
    for (int s = t; s < 8192; s += 1024) key[s] = cb[s];
    __syncthreads();
    for (int kk = 2048; kk <= 8192; kk <<= 1) {
        for (int j = kk >> 1; j > 0; j >>= 1) {
            for (int e = t; e < 8192; e += 1024) {
                int ixj = e ^ j;
                if (ixj > e) {
                    uint64_t a = key[e], c = key[ixj];
                    bool ddd = ((e & kk) == 0);
                    if ((a < c) == ddd) { key[e] = c; key[ixj] = a; }
                }
            }
            __syncthreads();
        }
    }
    // gather + decode (numpy op order; no FMA contraction)
    for (int r = t; r < KPAD2; r += 1024) {
        float4 bx = make_float4(0.f, 0.f, 0.f, 0.f);
        float sc = 0.f, ar = 0.f;
        if (r < KSEL) {
            uint64_t k64 = key[r];
            uint32_t idx = ~(uint32_t)(k64 & 0xFFFFFFFFull);
            sc = __uint_as_float((uint32_t)(k64 >> 32));
            size_t off = ((size_t)b << 18) + idx;
            float4 a = anchors[off];
            float4 d4 = rpn_bbox[off];
            float d0 = __fmul_rn(d4.x, 0.1f), d1 = __fmul_rn(d4.y, 0.1f);
            float d2 = __fmul_rn(d4.z, 0.2f), d3 = __fmul_rn(d4.w, 0.2f);
            float h = __fsub_rn(a.z, a.x), w = __fsub_rn(a.w, a.y);
            float cy = __fadd_rn(__fadd_rn(a.x, __fmul_rn(0.5f, h)), __fmul_rn(d0, h));
            float cx = __fadd_rn(__fadd_rn(a.y, __fmul_rn(0.5f, w)), __fmul_rn(d1, w));
            float h2 = __fmul_rn(h, expf(d2));
            float w2 = __fmul_rn(w, expf(d3));
            float y1 = __fsub_rn(cy, __fmul_rn(0.5f, h2));
            float x1 = __fsub_rn(cx, __fmul_rn(0.5f, w2));
            float y2 = __fadd_rn(cy, __fmul_rn(0.5f, h2));
            float x2 = __fadd_rn(cx, __fmul_rn(0.5f, w2));
            y1 = fminf(fmaxf(y1, 0.f), 1.f); x1 = fminf(fmaxf(x1, 0.f), 1.f);
            y2 = fminf(fmaxf(y2, 0.f), 1.f); x2 = fminf(fmaxf(x2, 0.f), 1.f);
            bx = make_float4(y1, x1, y2, x2);
            ar = __fmul_rn(__fsub_rn(y2, y1), __fsub_rn(x2, x1));
        }
        boxes[b * KPAD2 + r] = bx;
        scoresS[b * KPAD2 + r] = sc;
        areas[b * KPAD2 + r] = ar;
    }
}

// ---------- K5: suppression bit rows (256-wide words), 2 rows/thread ----------
__launch_bounds__(128)
__global__ void k_matrix(const float4* __restrict__ boxes, const float* __restrict__ areas,
                         uint64_t* __restrict__ mat, uint64_t* __restrict__ diag) {
    __shared__ float4 sb[256];
    __shared__ float sa[256];
    int q = blockIdx.x, b = blockIdx.y, t = threadIdx.x;
    int W, ibase;
    if (q < NW2) { W = q; ibase = W << 8; }
    else {
        int q2 = q - NW2; W = 1;
        while (q2 >= W) { q2 -= W; ++W; }
        ibase = q2 << 8;
    }
    size_t bb = (size_t)b * KPAD2;
    int j0 = W << 8;
    sb[t] = boxes[bb + j0 + t];
    sb[t + 128] = boxes[bb + j0 + t + 128];
    sa[t] = areas[bb + j0 + t];
    sa[t + 128] = areas[bb + j0 + t + 128];
    __syncthreads();
    int iA = ibase + t, iB = ibase + t + 128;
    float4 bA = boxes[bb + iA], bB = boxes[bb + iB];
    float aA = areas[bb + iA], aB = areas[bb + iB];
    uint32_t accA[8] = {0, 0, 0, 0, 0, 0, 0, 0};
    uint32_t accB[8] = {0, 0, 0, 0, 0, 0, 0, 0};
#pragma unroll 4
    for (int jj = 0; jj < 32; ++jj) {
#pragma unroll
        for (int s = 0; s < 4; ++s) {
            int j = (s << 6) + jj;
            float4 bj = sb[j]; float aj = sa[j];
            accA[s * 2] |= sup_bit(bA, aA, bj, aj) << jj;
            accB[s * 2] |= sup_bit(bB, aB, bj, aj) << jj;
        }
    }
#pragma unroll 4
    for (int jj = 32; jj < 64; ++jj) {
#pragma unroll
        for (int s = 0; s < 4; ++s) {
            int j = (s << 6) + jj;
            float4 bj = sb[j]; float aj = sa[j];
            accA[s * 2 + 1] |= sup_bit(bA, aA, bj, aj) << (jj - 32);
            accB[s * 2 + 1] |= sup_bit(bB, aB, bj, aj) << (jj - 32);
        }
    }
    uint64_t* rowA;
    uint64_t* rowB;
    if (q < NW2) {
        uint64_t dbase = (uint64_t)b * DIAG_U64_PB;
        rowA = diag + dbase + (uint64_t)iA * 4;
        rowB = diag + dbase + (uint64_t)iB * 4;
    } else {
        uint64_t mbase = (uint64_t)b * MAT_U64_PB + 512ull * W * (W - 1);
        rowA = mat + mbase + (uint64_t)iA * 4;
        rowB = mat + mbase + (uint64_t)iB * 4;
    }
    ulonglong2 vA0, vA1, vB0, vB1;
    vA0.x = (uint64_t)accA[0] | ((uint64_t)accA[1] << 32);
    vA0.y = (uint64_t)accA[2] | ((uint64_t)accA[3] << 32);
    vA1.x = (uint64_t)accA[4] | ((uint64_t)accA[5] << 32);
    vA1.y = (uint64_t)accA[6] | ((uint64_t)accA[7] << 32);
    vB0.x = (uint64_t)accB[0] | ((uint64_t)accB[1] << 32);
    vB0.y = (uint64_t)accB[2] | ((uint64_t)accB[3] << 32);
    vB1.x = (uint64_t)accB[4] | ((uint64_t)accB[5] << 32);
    vB1.y = (uint64_t)accB[6] | ((uint64_t)accB[7] << 32);
    ((ulonglong2*)rowA)[0] = vA0; ((ulonglong2*)rowA)[1] = vA1;
    ((ulonglong2*)rowB)[0] = vB0; ((ulonglong2*)rowB)[1] = vB1;
}

// ---------- K6: greedy NMS, 4 waves per batch (gather parallel, wave0 serial) ----------
__launch_bounds__(256)
__global__ void k_nms(const float4* __restrict__ boxes, const float* __restrict__ scoresS,
                      const uint64_t* __restrict__ diag, const uint64_t* __restrict__ mat,
                      float* __restrict__ out) {
    int b = blockIdx.x;
    int tid = threadIdx.x;
    int wid = tid >> 6, lane = tid & 63;
    __shared__ uint32_t sel[PROP];
    __shared__ uint32_t accs32[8];
    __shared__ uint32_t s_count;
    const uint64_t* mb = mat + (uint64_t)b * MAT_U64_PB;
    const ulonglong2* dp = (const ulonglong2*)(diag + (uint64_t)b * DIAG_U64_PB);
    if (tid == 0) s_count = 0;
    int count = 0;
    ulonglong2 d00, d01, d10, d11, d20, d21, d30, d31;
    for (int W = 0; W < NW2; ++W) {
        // wave 0: prefetch diag rows for this word (independent of accs)
        if (wid == 0) {
            int p0 = (W << 8) + lane;
            d00 = dp[p0 * 2];          d01 = dp[p0 * 2 + 1];
            d10 = dp[(p0 + 64) * 2];   d11 = dp[(p0 + 64) * 2 + 1];
            d20 = dp[(p0 + 128) * 2];  d21 = dp[(p0 + 128) * 2 + 1];
            d30 = dp[(p0 + 192) * 2];  d31 = dp[(p0 + 192) * 2 + 1];
        }
        if (tid < 8) accs32[tid] = 0u;
        __syncthreads();
        // gather suppression from prior selections: 4 independent slots over 256 threads
        uint64_t acc0 = 0, acc1 = 0, acc2 = 0, acc3 = 0;
        {
            const uint64_t* col = mb + 512ull * W * (W - 1);
            uint32_t c = (uint32_t)count;
            uint32_t i0 = tid, i1 = tid + 256, i2 = tid + 512, i3 = tid + 768;
            if (i0 < c) { const ulonglong2* r = (const ulonglong2*)(col + 4u * sel[i0]);
                          ulonglong2 x = r[0], y = r[1];
                          acc0 |= x.x; acc1 |= x.y; acc2 |= y.x; acc3 |= y.y; }
            if (i1 < c) { const ulonglong2* r = (const ulonglong2*)(col + 4u * sel[i1]);
                          ulonglong2 x = r[0], y = r[1];
                          acc0 |= x.x; acc1 |= x.y; acc2 |= y.x; acc3 |= y.y; }
            if (i2 < c) { const ulonglong2* r = (const ulonglong2*)(col + 4u * sel[i2]);
                          ulonglong2 x = r[0], y = r[1];
                          acc0 |= x.x; acc1 |= x.y; acc2 |= y.x; acc3 |= y.y; }
            if (i3 < c) { const ulonglong2* r = (const ulonglong2*)(col + 4u * sel[i3]);
                          ulonglong2 x = r[0], y = r[1];
                          acc0 |= x.x; acc1 |= x.y; acc2 |= y.x; acc3 |= y.y; }
        }
#pragma unroll
        for (int off = 32; off; off >>= 1) {
            acc0 |= shfl_xor_u64(acc0, off);
            acc1 |= shfl_xor_u64(acc1, off);
            acc2 |= shfl_xor_u64(acc2, off);
            acc3 |= shfl_xor_u64(acc3, off);
        }
        if (lane == 0) {
            if (acc0) { atomicOr(&accs32[0], (uint32_t)acc0); atomicOr(&accs32[1], (uint32_t)(acc0 >> 32)); }
            if (acc1) { atomicOr(&accs32[2], (uint32_t)acc1); atomicOr(&accs32[3], (uint32_t)(acc1 >> 32)); }
            if (acc2) { atomicOr(&accs32[4], (uint32_t)acc2); atomicOr(&accs32[5], (uint32_t)(acc2 >> 32)); }
            if (acc3) { atomicOr(&accs32[6], (uint32_t)acc3); atomicOr(&accs32[7], (uint32_t)(acc3 >> 32)); }
        }
        __syncthreads();
        if (wid == 0) {
            uint64_t a0 = ~(((uint64_t)accs32[1] << 32) | accs32[0]);
            uint64_t a1 = ~(((uint64_t)accs32[3] << 32) | accs32[2]);
            uint64_t a2 = ~(((uint64_t)accs32[5] << 32) | accs32[4]);
            uint64_t a3 = ~(((uint64_t)accs32[7] << 32) | accs32[6]);
            if (W == NW2 - 1) { a1 &= (1ull << 48) - 1; a2 = 0; a3 = 0; }   // j < 6000 valid

#define SUBWORD(S, AS, R0, R1, R2, R3)                                       \
            while (AS && count < PROP) {                                     \
                uint32_t bp = (uint32_t)__builtin_ctzll(AS);                 \
                if (lane == 0) sel[count] = (uint32_t)((W << 8) + (S << 6) + bp);\
                uint64_t q0 = rdlane64(R0, bp), q1 = rdlane64(R1, bp);       \
                uint64_t q2v = rdlane64(R2, bp), q3 = rdlane64(R3, bp);      \
                a0 &= ~q0; a1 &= ~q1; a2 &= ~q2v; a3 &= ~q3;                 \
                AS &= ~(1ull << bp);                                         \
                ++count;                                                     \
            }
            SUBWORD(0, a0, d00.x, d00.y, d01.x, d01.y)
            SUBWORD(1, a1, d10.x, d10.y, d11.x, d11.y)
            SUBWORD(2, a2, d20.x, d20.y, d21.x, d21.y)
            SUBWORD(3, a3, d30.x, d30.y, d31.x, d31.y)
#undef SUBWORD
            if (lane == 0) s_count = (uint32_t)count;
        }
        __syncthreads();
        count = (int)s_count;
        if (count >= PROP) break;
    }
    __syncthreads();
    // parallel output epilogue
    float* prop = out + b * (PROP * 4);
    float* psc = out + BB * PROP * 4 + b * PROP;
    for (int r = tid; r < PROP; r += 256) {
        if (r < count) {
            uint32_t j = sel[r];
            float4 bx = boxes[(size_t)b * KPAD2 + j];
            *(float4*)(prop + r * 4) = bx;
            psc[r] = scoresS[(size_t)b * KPAD2 + j];
        } else {
            *(float4*)(prop + r * 4) = make_float4(0.f, 0.f, 0.f, 0.f);
            psc[r] = 0.f;
        }
    }
}

extern "C" void kernel_launch(void* const* d_in, const int* in_sizes, int n_in,
                              void* d_out, int out_size, void* d_ws, size_t ws_size,
                              hipStream_t stream) {
    const float4* probs = (const float4*)d_in[0];
    const float4* rpn_bbox = (const float4*)d_in[1];
    const float4* anchors = (const float4*)d_in[2];
    float* out = (float*)d_out;

    uint8_t* p = (uint8_t*)d_ws;
    size_t off = 0;
    auto alloc = [&](size_t bytes) -> void* {
        void* q = p + off;
        off += (bytes + 255) & ~(size_t)255;
        return q;
    };
    uint32_t* ghist = (uint32_t*)alloc((size_t)BB * 256 * 4);
    uint32_t* cnt = (uint32_t*)alloc(BB * 4);
    uint64_t* cand = (uint64_t*)alloc((size_t)BB * CAND_CAP * 8);          // 512 KB
    float4* boxes = (float4*)alloc((size_t)BB * KPAD2 * 16);               // 768 KB
    float* scoresS = (float*)alloc((size_t)BB * KPAD2 * 4);
    float* areas = (float*)alloc((size_t)BB * KPAD2 * 4);
    uint64_t* diag = (uint64_t*)alloc((size_t)BB * DIAG_U64_PB * 8);       // 1.57 MB
    uint64_t* mat = (uint64_t*)alloc((size_t)BB * MAT_U64_PB * 8);         // 18.1 MB

    if (off > ws_size) {
        hipMemsetAsync(d_out, 0, (size_t)out_size * 4, stream);
        return;
    }

    hipMemsetAsync(ghist, 0, (size_t)BB * 256 * 4 + 512, stream);

    k_hist<<<BB * BPB, 256, 0, stream>>>(probs, ghist);
    k_compact<<<BB * BPB, 256, 0, stream>>>(probs, ghist, cnt, cand);
    dim3 gs1(8, BB);
    k_sort1<<<gs1, 256, 0, stream>>>(cnt, cand);
    k_sort2<<<BB, 1024, 0, stream>>>(cand, rpn_bbox, anchors, boxes, scoresS, areas);
    dim3 gm(NW2 + 276, BB);   // 24 diag chunks + sum_{W=1..23} W off-diag chunks
    k_matrix<<<gm, 128, 0, stream>>>(boxes, areas, mat, diag);
    k_nms<<<BB, 256, 0, stream>>>(boxes, scoresS, diag, mat, out);
}

// Round 6
// 296.076 us; speedup vs baseline: 3.8254x; 1.0044x over previous
//
#include <hip/hip_runtime.h>
#include <stdint.h>

#define BB 8
#define NN 262144
#define KSEL 6000
#define KPAD2 6144
#define NW2 24               // 24 words of 256 boxes
#define PROP 1000
#define NMS_THR 0.7f
#define CAND_CAP 8192
#define BPB 64               // blocks per batch for hist/compact (4096 items each)
#define STAGE_CAP 768
#define MAT_U64_PB 282624ull // sum_{W=1..23} 256*W rows * 4 u64 = 512*23*24
#define DIAG_U64_PB 24576ull // 24*256*4

// ---------- helpers ----------
__device__ __forceinline__ unsigned long long shfl_xor_u64(unsigned long long v, int m) {
    unsigned lo = (unsigned)v, hi = (unsigned)(v >> 32);
    lo = __shfl_xor(lo, m);
    hi = __shfl_xor(hi, m);
    return ((unsigned long long)hi << 32) | lo;
}

// Exact replacement for RN(inter/den) > 0.7f (den > 0 always):
//   RN(q) > c  <=>  q >= M, M = c + 2^-25 (midpoint; tie rounds to even = c_next > c).
//   M has 25-bit significand, den 24 bits -> M*den exact in f64; comparison exact.
__device__ __forceinline__ uint32_t sup_bit(const float4 bi, float ai, const float4 bj, float aj) {
    float y1 = fmaxf(bi.x, bj.x), x1 = fmaxf(bi.y, bj.y);
    float y2 = fminf(bi.z, bj.z), x2 = fminf(bi.w, bj.w);
    float inter = __fmul_rn(fmaxf(__fsub_rn(y2, y1), 0.f), fmaxf(__fsub_rn(x2, x1), 0.f));
    float den = __fadd_rn(__fsub_rn(__fadd_rn(ai, aj), inter), 1e-10f);
    const double MSUP = 23488103.0 / 33554432.0;   // 0.7f + 2^-25, exact
    return (double)inter >= MSUP * (double)den;
}

__device__ __forceinline__ uint32_t score_bin(float sc) {
    uint32_t u = (uint32_t)(sc * 16777216.0f);
    u = u > 16777215u ? 16777215u : u;
    return u >> 16;
}

// ---------- K1: per-block LDS histogram -> global 256-bin per-batch hist ----------
__global__ void k_hist(const float4* __restrict__ probs, uint32_t* __restrict__ ghist) {
    __shared__ uint32_t lh[256];
    int blk = blockIdx.x;
    int b = blk >> 6;
    int t = threadIdx.x;
    lh[t] = 0u;
    __syncthreads();
    size_t fbase = ((size_t)b * (NN / 2)) + (size_t)(blk & 63) * 2048;
#pragma unroll
    for (int k = 0; k < 8; ++k) {
        float4 v = probs[fbase + k * 256 + t];
        atomicAdd(&lh[score_bin(v.y)], 1u);
        atomicAdd(&lh[score_bin(v.w)], 1u);
    }
    __syncthreads();
    uint32_t c = lh[t];
    if (c) atomicAdd(&ghist[(b << 8) + t], c);
}

// ---------- K3: compact candidates (threshold derived in-block), block-aggregated ----------
__global__ void k_compact(const float4* __restrict__ probs, const uint32_t* __restrict__ ghist,
                          uint32_t* __restrict__ cnt, uint64_t* __restrict__ cand) {
    __shared__ uint64_t stage[STAGE_CAP];
    __shared__ uint32_t lh[256];
    __shared__ uint32_t s_bst, lcnt, lbase;
    int blk = blockIdx.x;
    int b = blk >> 6;
    int t = threadIdx.x;
    lh[t] = ghist[(b << 8) + t];
    if (t == 0) lcnt = 0u;
    __syncthreads();
    if (t == 0) {
        uint32_t cum = 0; uint32_t bst = 0;
        for (int c = 255; c >= 0; --c) {
            cum += lh[c];
            if (cum >= (uint32_t)KSEL) { bst = (uint32_t)c; break; }
        }
        s_bst = bst;
    }
    __syncthreads();
    uint32_t bst = s_bst;
    int ibase = (blk & 63) * 4096;
    size_t fbase = ((size_t)b * (NN / 2)) + (size_t)(blk & 63) * 2048;
#pragma unroll
    for (int k = 0; k < 8; ++k) {
        float4 v = probs[fbase + k * 256 + t];
        int i0 = ibase + (k * 256 + t) * 2;
#pragma unroll
        for (int e = 0; e < 2; ++e) {
            float sc = e ? v.w : v.y;
            if (score_bin(sc) >= bst) {
                uint32_t p = atomicAdd(&lcnt, 1u);
                if (p < STAGE_CAP) {
                    uint32_t bits = __float_as_uint(sc);
                    stage[p] = ((uint64_t)bits << 32) | (uint32_t)(~(uint32_t)(i0 + e));
                }
            }
        }
    }
    __syncthreads();
    if (t == 0) {
        uint32_t m = lcnt > STAGE_CAP ? STAGE_CAP : lcnt;
        lbase = atomicAdd(&cnt[b], m);
        lcnt = m;
    }
    __syncthreads();
    uint32_t m = lcnt, base = lbase;
    for (uint32_t s = t; s < m; s += 256) {
        uint32_t pos = base + s;
        if (pos < CAND_CAP) cand[((uint64_t)b << 13) + pos] = stage[s];
    }
}

// ---------- K4a: bitonic phase A — sort 1024-chunks (stages kk=2..1024) ----------
__launch_bounds__(256)
__global__ void k_sort1(const uint32_t* __restrict__ cnt, uint64_t* __restrict__ cand) {
    __shared__ uint64_t key[1024];
    int b = blockIdx.y, ch = blockIdx.x, t = threadIdx.x;
    uint32_t M = cnt[b]; if (M > CAND_CAP) M = CAND_CAP;
    uint64_t* cb = cand + ((uint64_t)b << 13);
    int base = ch << 10;
    for (int i = t; i < 1024; i += 256) key[i] = ((uint32_t)(base + i) < M) ? cb[base + i] : 0ull;
    __syncthreads();
    for (int kk = 2; kk <= 1024; kk <<= 1) {
        for (int j = kk >> 1; j > 0; j >>= 1) {
            for (int e = t; e < 1024; e += 256) {
                int ixj = e ^ j;
                if (ixj > e) {
                    uint64_t a = key[e], c = key[ixj];
                    bool ddd = (((base + e) & kk) == 0);   // global-e direction
                    if ((a < c) == ddd) { key[e] = c; key[ixj] = a; }
                }
            }
            __syncthreads();
        }
    }
    for (int i = t; i < 1024; i += 256) cb[base + i] = key[i];
}

// ---------- K4b: bitonic merge (kk=2048..8192) + gather + decode ----------
__launch_bounds__(1024)
__global__ void k_sort2(const uint64_t* __restrict__ cand,
                        const float4* __restrict__ rpn_bbox, const float4* __restrict__ anchors,
                        float4* __restrict__ boxes, float* __restrict__ scoresS,
                        float* __restrict__ areas) {
    __shared__ uint64_t key[8192];
    int b = blockIdx.x, t = threadIdx.x;
    const uint64_t* cb = cand + ((uint64_t)b << 13);
    for (int s = t; s < 8192; s += 1024) key[s] = cb[s];
    __syncthreads();
    for (int kk = 2048; kk <= 8192; kk <<= 1) {
        for (int j = kk >> 1; j > 0; j >>= 1) {
            for (int e = t; e < 8192; e += 1024) {
                int ixj = e ^ j;
                if (ixj > e) {
                    uint64_t a = key[e], c = key[ixj];
                    bool ddd = ((e & kk) == 0);
                    if ((a < c) == ddd) { key[e] = c; key[ixj] = a; }
                }
            }
            __syncthreads();
        }
    }
    // gather + decode (numpy op order; no FMA contraction)
    for (int r = t; r < KPAD2; r += 1024) {
        float4 bx = make_float4(0.f, 0.f, 0.f, 0.f);
        float sc = 0.f, ar = 0.f;
        if (r < KSEL) {
            uint64_t k64 = key[r];
            uint32_t idx = ~(uint32_t)(k64 & 0xFFFFFFFFull);
            sc = __uint_as_float((uint32_t)(k64 >> 32));
            size_t off = ((size_t)b << 18) + idx;
            float4 a = anchors[off];
            float4 d4 = rpn_bbox[off];
            float d0 = __fmul_rn(d4.x, 0.1f), d1 = __fmul_rn(d4.y, 0.1f);
            float d2 = __fmul_rn(d4.z, 0.2f), d3 = __fmul_rn(d4.w, 0.2f);
            float h = __fsub_rn(a.z, a.x), w = __fsub_rn(a.w, a.y);
            float cy = __fadd_rn(__fadd_rn(a.x, __fmul_rn(0.5f, h)), __fmul_rn(d0, h));
            float cx = __fadd_rn(__fadd_rn(a.y, __fmul_rn(0.5f, w)), __fmul_rn(d1, w));
            float h2 = __fmul_rn(h, expf(d2));
            float w2 = __fmul_rn(w, expf(d3));
            float y1 = __fsub_rn(cy, __fmul_rn(0.5f, h2));
            float x1 = __fsub_rn(cx, __fmul_rn(0.5f, w2));
            float y2 = __fadd_rn(cy, __fmul_rn(0.5f, h2));
            float x2 = __fadd_rn(cx, __fmul_rn(0.5f, w2));
            y1 = fminf(fmaxf(y1, 0.f), 1.f); x1 = fminf(fmaxf(x1, 0.f), 1.f);
            y2 = fminf(fmaxf(y2, 0.f), 1.f); x2 = fminf(fmaxf(x2, 0.f), 1.f);
            bx = make_float4(y1, x1, y2, x2);
            ar = __fmul_rn(__fsub_rn(y2, y1), __fsub_rn(x2, x1));
        }
        boxes[b * KPAD2 + r] = bx;
        scoresS[b * KPAD2 + r] = sc;
        areas[b * KPAD2 + r] = ar;
    }
}

// ---------- K5: suppression bit rows (256-wide words), 2 rows/thread ----------
__launch_bounds__(128)
__global__ void k_matrix(const float4* __restrict__ boxes, const float* __restrict__ areas,
                         uint64_t* __restrict__ mat, uint64_t* __restrict__ diag) {
    __shared__ float4 sb[256];
    __shared__ float sa[256];
    int q = blockIdx.x, b = blockIdx.y, t = threadIdx.x;
    int W, ibase;
    if (q < NW2) { W = q; ibase = W << 8; }
    else {
        int q2 = q - NW2; W = 1;
        while (q2 >= W) { q2 -= W; ++W; }
        ibase = q2 << 8;
    }
    size_t bb = (size_t)b * KPAD2;
    int j0 = W << 8;
    sb[t] = boxes[bb + j0 + t];
    sb[t + 128] = boxes[bb + j0 + t + 128];
    sa[t] = areas[bb + j0 + t];
    sa[t + 128] = areas[bb + j0 + t + 128];
    __syncthreads();
    int iA = ibase + t, iB = ibase + t + 128;
    float4 bA = boxes[bb + iA], bB = boxes[bb + iB];
    float aA = areas[bb + iA], aB = areas[bb + iB];
    uint32_t accA[8] = {0, 0, 0, 0, 0, 0, 0, 0};
    uint32_t accB[8] = {0, 0, 0, 0, 0, 0, 0, 0};
#pragma unroll 4
    for (int jj = 0; jj < 32; ++jj) {
#pragma unroll
        for (int s = 0; s < 4; ++s) {
            int j = (s << 6) + jj;
            float4 bj = sb[j]; float aj = sa[j];
            accA[s * 2] |= sup_bit(bA, aA, bj, aj) << jj;
            accB[s * 2] |= sup_bit(bB, aB, bj, aj) << jj;
        }
    }
#pragma unroll 4
    for (int jj = 32; jj < 64; ++jj) {
#pragma unroll
        for (int s = 0; s < 4; ++s) {
            int j = (s << 6) + jj;
            float4 bj = sb[j]; float aj = sa[j];
            accA[s * 2 + 1] |= sup_bit(bA, aA, bj, aj) << (jj - 32);
            accB[s * 2 + 1] |= sup_bit(bB, aB, bj, aj) << (jj - 32);
        }
    }
    uint64_t* rowA;
    uint64_t* rowB;
    if (q < NW2) {
        uint64_t dbase = (uint64_t)b * DIAG_U64_PB;
        rowA = diag + dbase + (uint64_t)iA * 4;
        rowB = diag + dbase + (uint64_t)iB * 4;
    } else {
        uint64_t mbase = (uint64_t)b * MAT_U64_PB + 512ull * W * (W - 1);
        rowA = mat + mbase + (uint64_t)iA * 4;
        rowB = mat + mbase + (uint64_t)iB * 4;
    }
    ulonglong2 vA0, vA1, vB0, vB1;
    vA0.x = (uint64_t)accA[0] | ((uint64_t)accA[1] << 32);
    vA0.y = (uint64_t)accA[2] | ((uint64_t)accA[3] << 32);
    vA1.x = (uint64_t)accA[4] | ((uint64_t)accA[5] << 32);
    vA1.y = (uint64_t)accA[6] | ((uint64_t)accA[7] << 32);
    vB0.x = (uint64_t)accB[0] | ((uint64_t)accB[1] << 32);
    vB0.y = (uint64_t)accB[2] | ((uint64_t)accB[3] << 32);
    vB1.x = (uint64_t)accB[4] | ((uint64_t)accB[5] << 32);
    vB1.y = (uint64_t)accB[6] | ((uint64_t)accB[7] << 32);
    ((ulonglong2*)rowA)[0] = vA0; ((ulonglong2*)rowA)[1] = vA1;
    ((ulonglong2*)rowB)[0] = vB0; ((ulonglong2*)rowB)[1] = vB1;
}

// ---------- K6: greedy NMS, 4 waves/batch; ballot-based selection (IoU symmetric) ----------
__launch_bounds__(256)
__global__ void k_nms(const float4* __restrict__ boxes, const float* __restrict__ scoresS,
                      const uint64_t* __restrict__ diag, const uint64_t* __restrict__ mat,
                      float* __restrict__ out) {
    int b = blockIdx.x;
    int tid = threadIdx.x;
    int wid = tid >> 6, lane = tid & 63;
    __shared__ uint32_t sel[PROP];
    __shared__ uint32_t accs32[8];
    __shared__ uint32_t s_count;
    const uint64_t* mb = mat + (uint64_t)b * MAT_U64_PB;
    const ulonglong2* dp = (const ulonglong2*)(diag + (uint64_t)b * DIAG_U64_PB);
    if (tid == 0) s_count = 0;
    int count = 0;
    ulonglong2 d00, d01, d10, d11, d20, d21, d30, d31;
    for (int W = 0; W < NW2; ++W) {
        // wave 0: load own-position diag rows for this word
        // lane holds rows for its positions lane, 64+lane, 128+lane, 192+lane.
        // By IoU symmetry, bit bp of word t of MY row == "selected box (t,bp) suppresses me".
        if (wid == 0) {
            int p0 = (W << 8) + lane;
            d00 = dp[p0 * 2];          d01 = dp[p0 * 2 + 1];
            d10 = dp[(p0 + 64) * 2];   d11 = dp[(p0 + 64) * 2 + 1];
            d20 = dp[(p0 + 128) * 2];  d21 = dp[(p0 + 128) * 2 + 1];
            d30 = dp[(p0 + 192) * 2];  d31 = dp[(p0 + 192) * 2 + 1];
        }
        if (tid < 8) accs32[tid] = 0u;
        __syncthreads();
        // gather suppression from prior selections: 4 independent slots over 256 threads
        uint64_t acc0 = 0, acc1 = 0, acc2 = 0, acc3 = 0;
        {
            const uint64_t* col = mb + 512ull * W * (W - 1);
            uint32_t c = (uint32_t)count;
            uint32_t i0 = tid, i1 = tid + 256, i2 = tid + 512, i3 = tid + 768;
            if (i0 < c) { const ulonglong2* r = (const ulonglong2*)(col + 4u * sel[i0]);
                          ulonglong2 x = r[0], y = r[1];
                          acc0 |= x.x; acc1 |= x.y; acc2 |= y.x; acc3 |= y.y; }
            if (i1 < c) { const ulonglong2* r = (const ulonglong2*)(col + 4u * sel[i1]);
                          ulonglong2 x = r[0], y = r[1];
                          acc0 |= x.x; acc1 |= x.y; acc2 |= y.x; acc3 |= y.y; }
            if (i2 < c) { const ulonglong2* r = (const ulonglong2*)(col + 4u * sel[i2]);
                          ulonglong2 x = r[0], y = r[1];
                          acc0 |= x.x; acc1 |= x.y; acc2 |= y.x; acc3 |= y.y; }
            if (i3 < c) { const ulonglong2* r = (const ulonglong2*)(col + 4u * sel[i3]);
                          ulonglong2 x = r[0], y = r[1];
                          acc0 |= x.x; acc1 |= x.y; acc2 |= y.x; acc3 |= y.y; }
        }
#pragma unroll
        for (int off = 32; off; off >>= 1) {
            acc0 |= shfl_xor_u64(acc0, off);
            acc1 |= shfl_xor_u64(acc1, off);
            acc2 |= shfl_xor_u64(acc2, off);
            acc3 |= shfl_xor_u64(acc3, off);
        }
        if (lane == 0) {
            if (acc0) { atomicOr(&accs32[0], (uint32_t)acc0); atomicOr(&accs32[1], (uint32_t)(acc0 >> 32)); }
            if (acc1) { atomicOr(&accs32[2], (uint32_t)acc1); atomicOr(&accs32[3], (uint32_t)(acc1 >> 32)); }
            if (acc2) { atomicOr(&accs32[4], (uint32_t)acc2); atomicOr(&accs32[5], (uint32_t)(acc2 >> 32)); }
            if (acc3) { atomicOr(&accs32[6], (uint32_t)acc3); atomicOr(&accs32[7], (uint32_t)(acc3 >> 32)); }
        }
        __syncthreads();
        if (wid == 0) {
            uint64_t a0 = ~(((uint64_t)accs32[1] << 32) | accs32[0]);
            uint64_t a1 = ~(((uint64_t)accs32[3] << 32) | accs32[2]);
            uint64_t a2 = ~(((uint64_t)accs32[5] << 32) | accs32[4]);
            uint64_t a3 = ~(((uint64_t)accs32[7] << 32) | accs32[6]);
            if (W == NW2 - 1) { a1 &= (1ull << 48) - 1; a2 = 0; a3 = 0; }   // j < 6000 valid

            // Ballot selection: each lane tests bit bp of its OWN word-S row;
            // ballot reassembles the suppressed-mask for all 4 subwords.
#define SUBWORD(S, AS, R0, R1, R2, R3)                                       \
            while (AS && count < PROP) {                                     \
                uint32_t bp = (uint32_t)__builtin_ctzll(AS);                 \
                bp = __builtin_amdgcn_readfirstlane(bp);                     \
                if (lane == 0) sel[count] = (uint32_t)((W << 8) + (S << 6) + bp);\
                unsigned long long m0 = __ballot(((R0 >> bp) & 1ull) != 0);  \
                unsigned long long m1 = __ballot(((R1 >> bp) & 1ull) != 0);  \
                unsigned long long m2 = __ballot(((R2 >> bp) & 1ull) != 0);  \
                unsigned long long m3 = __ballot(((R3 >> bp) & 1ull) != 0);  \
                a0 &= ~m0; a1 &= ~m1; a2 &= ~m2; a3 &= ~m3;                  \
                AS &= ~(1ull << bp);                                         \
                ++count;                                                     \
            }
            SUBWORD(0, a0, d00.x, d10.x, d20.x, d30.x)
            SUBWORD(1, a1, d00.y, d10.y, d20.y, d30.y)
            SUBWORD(2, a2, d01.x, d11.x, d21.x, d31.x)
            SUBWORD(3, a3, d01.y, d11.y, d21.y, d31.y)
#undef SUBWORD
            if (lane == 0) s_count = (uint32_t)count;
        }
        __syncthreads();
        count = (int)s_count;
        if (count >= PROP) break;
    }
    __syncthreads();
    // parallel output epilogue
    float* prop = out + b * (PROP * 4);
    float* psc = out + BB * PROP * 4 + b * PROP;
    for (int r = tid; r < PROP; r += 256) {
        if (r < count) {
            uint32_t j = sel[r];
            float4 bx = boxes[(size_t)b * KPAD2 + j];
            *(float4*)(prop + r * 4) = bx;
            psc[r] = scoresS[(size_t)b * KPAD2 + j];
        } else {
            *(float4*)(prop + r * 4) = make_float4(0.f, 0.f, 0.f, 0.f);
            psc[r] = 0.f;
        }
    }
}

extern "C" void kernel_launch(void* const* d_in, const int* in_sizes, int n_in,
                              void* d_out, int out_size, void* d_ws, size_t ws_size,
                              hipStream_t stream) {
    const float4* probs = (const float4*)d_in[0];
    const float4* rpn_bbox = (const float4*)d_in[1];
    const float4* anchors = (const float4*)d_in[2];
    float* out = (float*)d_out;

    uint8_t* p = (uint8_t*)d_ws;
    size_t off = 0;
    auto alloc = [&](size_t bytes) -> void* {
        void* q = p + off;
        off += (bytes + 255) & ~(size_t)255;
        return q;
    };
    uint32_t* ghist = (uint32_t*)alloc((size_t)BB * 256 * 4);
    uint32_t* cnt = (uint32_t*)alloc(BB * 4);
    uint64_t* cand = (uint64_t*)alloc((size_t)BB * CAND_CAP * 8);          // 512 KB
    float4* boxes = (float4*)alloc((size_t)BB * KPAD2 * 16);               // 768 KB
    float* scoresS = (float*)alloc((size_t)BB * KPAD2 * 4);
    float* areas = (float*)alloc((size_t)BB * KPAD2 * 4);
    uint64_t* diag = (uint64_t*)alloc((size_t)BB * DIAG_U64_PB * 8);       // 1.57 MB
    uint64_t* mat = (uint64_t*)alloc((size_t)BB * MAT_U64_PB * 8);         // 18.1 MB

    if (off > ws_size) {
        hipMemsetAsync(d_out, 0, (size_t)out_size * 4, stream);
        return;
    }

    hipMemsetAsync(ghist, 0, (size_t)BB * 256 * 4 + 512, stream);

    k_hist<<<BB * BPB, 256, 0, stream>>>(probs, ghist);
    k_compact<<<BB * BPB, 256, 0, stream>>>(probs, ghist, cnt, cand);
    dim3 gs1(8, BB);
    k_sort1<<<gs1, 256, 0, stream>>>(cnt, cand);
    k_sort2<<<BB, 1024, 0, stream>>>(cand, rpn_bbox, anchors, boxes, scoresS, areas);
    dim3 gm(NW2 + 276, BB);   // 24 diag chunks + sum_{W=1..23} W off-diag chunks
    k_matrix<<<gm, 128, 0, stream>>>(boxes, areas, mat, diag);
    k_nms<<<BB, 256, 0, stream>>>(boxes, scoresS, diag, mat, out);
}